// Round 4
// baseline (639.304 us; speedup 1.0000x reference)
//
#include <hip/hip_runtime.h>
#include <hip/hip_bf16.h>
#include <float.h>
#include <math.h>

// Problem constants
#define NB      4
#define QN      128
#define HID     512
#define NMEM    20000
#define MPAD    20096    // 157*128
#define NCHUNK  625
#define CHUNK   32
#define HEADS   8
#define DHEAD   64
#define TOPKK   8
#define NKV     1024   // 2*HEADS*DHEAD
#define LOGIT_SCALE 0.044194173824159216f  // 512^-0.5
#define W2LD    576    // W2buf / u_ext leading dim (512 + 1 alpha col + pad)
#define STROWS  520    // summText rows: 512 + ones row + 7 zero rows
#define LGLD    640    // logits leading dim

typedef __attribute__((ext_vector_type(8))) short bf16x8;
typedef __attribute__((ext_vector_type(4))) float f32x4;

__device__ __forceinline__ short f2bf(float f){
  __hip_bfloat16 h = __float2bfloat16(f);
  return *reinterpret_cast<short*>(&h);
}
__device__ __forceinline__ float bf2f(unsigned short s){
  __hip_bfloat16 h;
  *reinterpret_cast<unsigned short*>(&h) = s;
  return __bfloat162float(h);
}
__device__ __forceinline__ bool mask_at(const void* m, int flag, long i){
  return flag ? (((const unsigned char*)m)[i] != 0)
              : (((const int*)m)[i] != 0);
}
__device__ __forceinline__ void gload16(const void* g, void* l){
  __builtin_amdgcn_global_load_lds((const __attribute__((address_space(1))) void*)g,
                                   (__attribute__((address_space(3))) void*)l, 16, 0, 0);
}

// ---------------- misc: pos table + mask-layout flag ----------------
__global__ __launch_bounds__(512) void misc_kernel(float* __restrict__ pos,
                                                   int* __restrict__ flagp,
                                                   const void* __restrict__ mask){
  int c = blockIdx.x;      // 0..31
  int d = threadIdx.x;     // 0..511
  int j = (d < 256) ? d : d - 256;
  float invf = expf(-((2.0f * (float)j) / 512.0f) * 9.2103403719761836f);
  float arg = (float)(31 - c) * invf;
  pos[c * 512 + d] = (d < 256) ? sinf(arg) : cosf(arg);
  if (c == 0 && d == 0){
    const unsigned char* mb = (const unsigned char*)mask;
    *flagp = (mb[1] != 0) ? 1 : 0;
  }
}

// ---------------- fold out_w @ fc2_w ----------------
__global__ __launch_bounds__(512) void fold_kernel(const float* __restrict__ out_w,
                                                   const float* __restrict__ out_b,
                                                   const float* __restrict__ fc2_w,
                                                   const float* __restrict__ fc2_b,
                                                   float* __restrict__ Wf,
                                                   float* __restrict__ bf){
  int j = blockIdx.x;   // 0..4
  int d = threadIdx.x;  // 0..511
  float s = 0.f;
  for (int k = 0; k < 512; ++k) s += out_w[d * 512 + k] * fc2_w[k * 5 + j];
  Wf[d * 5 + j] = s;
  if (d == 0){
    float sb = 0.f;
    for (int k = 0; k < 512; ++k) sb += out_b[k] * fc2_w[k * 5 + j];
    bf[j] = sb + fc2_b[j];
  }
}

// ---------------- kv_w transpose -> bf16 Bt[1024][512] ----------------
__global__ __launch_bounds__(256) void wtr_kernel(const float* __restrict__ kvw,
                                                  unsigned short* __restrict__ Bt){
  long id = (long)blockIdx.x * 256 + threadIdx.x;   // 524288 total
  int n = (int)(id >> 9), k = (int)(id & 511);
  Bt[id] = (unsigned short)f2bf(kvw[(long)k * NKV + n]);
}

// ---------------- sk_w transpose (f32): skwT[j][e] = sk_w[e][j] ----------------
__global__ __launch_bounds__(256) void skwt_kernel(const float* __restrict__ skw,
                                                   float* __restrict__ skwT){
  long id = (long)blockIdx.x * 256 + threadIdx.x;   // 262144
  int e = (int)(id >> 9), j = (int)(id & 511);
  skwT[(long)j * 512 + e] = skw[id];
}

// ---------------- fused: memories -> summ + chunkden + bf16 (mem+pos) ----------------
// grid (626, NB), 256 threads. Block (n<625): one chunk (32 rows x 512).
// Thread t: rows rh, rh+2, ..., rh+30 (rh = t>>7), float4 col group c4 = t&127.
// Block n==625: zero pad rows NMEM..MPAD-1 (only when abf != nullptr).
__global__ __launch_bounds__(256) void prepsum_kernel(const float* __restrict__ memories,
                                                      const float* __restrict__ pos,
                                                      const void* __restrict__ mask,
                                                      const int* __restrict__ flagp,
                                                      unsigned short* __restrict__ abf_all,
                                                      float* __restrict__ summ,
                                                      float* __restrict__ chunkden){
  int n = blockIdx.x, b = blockIdx.y;
  int t = threadIdx.x;
  unsigned short* abf = abf_all ? abf_all + (long)b * MPAD * 512 : nullptr;
  if (n == NCHUNK){
    if (abf){
      for (int idx = t; idx < 96 * 128; idx += 256){
        ushort4 z = {0, 0, 0, 0};
        *(ushort4*)(abf + (long)(NMEM + (idx >> 7)) * 512 + (long)(idx & 127) * 4) = z;
      }
    }
    return;
  }
  int flag = *flagp;
  long mbase = (long)b * NMEM + (long)n * CHUNK;
  unsigned int m32 = 0;
  for (int c = 0; c < 32; ++c) m32 |= (mask_at(mask, flag, mbase + c) ? 1u : 0u) << c;
  float den = (float)__popc(m32);
  int c4 = t & 127;
  int rh = t >> 7;
  const float* base = memories + mbase * HID;
  float4 acc = {0.f, 0.f, 0.f, 0.f};
#pragma unroll
  for (int c = rh; c < 32; c += 2){
    float4 v  = *(const float4*)(base + (long)c * HID + c4 * 4);
    if (abf){
      float4 p4 = *(const float4*)(pos + c * HID + c4 * 4);
      ushort4 o;
      o.x = (unsigned short)f2bf(v.x + p4.x);
      o.y = (unsigned short)f2bf(v.y + p4.y);
      o.z = (unsigned short)f2bf(v.z + p4.z);
      o.w = (unsigned short)f2bf(v.w + p4.w);
      *(ushort4*)(abf + (long)(n * CHUNK + c) * 512 + c4 * 4) = o;
    }
    if (m32 & (1u << c)){
      acc.x += v.x; acc.y += v.y; acc.z += v.z; acc.w += v.w;
    }
  }
  __shared__ float4 red[256];
  red[t] = acc;
  __syncthreads();
  if (rh == 0){
    float4 a = red[t], bq = red[t + 128];
    float dv = den + 1e-5f;
    float4 s4;
    s4.x = (a.x + bq.x) / dv;
    s4.y = (a.y + bq.y) / dv;
    s4.z = (a.z + bq.z) / dv;
    s4.w = (a.w + bq.w) / dv;
    *(float4*)(summ + ((long)b * NCHUNK + n) * 512 + c4 * 4) = s4;
    if (t == 0) chunkden[b * NCHUNK + n] = den;
  }
}

// ---------------- prep (fallback path): (mem+pos) -> bf16 A[MPAD][512] ----------------
__global__ __launch_bounds__(256) void prep_kernel(const float* __restrict__ mem,
                                                   const float* __restrict__ pos,
                                                   unsigned short* __restrict__ Abf){
  long idx = (long)blockIdx.x * 256 + threadIdx.x;  // MPAD*512/4 = 2,572,288
  int r = (int)(idx >> 7);
  int cv = (int)(idx & 127) << 2;
  ushort4 o;
  if (r < NMEM){
    float4 m4 = *(const float4*)(mem + (long)r * 512 + cv);
    float4 p4 = *(const float4*)(pos + (r & 31) * 512 + cv);
    o.x = (unsigned short)f2bf(m4.x + p4.x);
    o.y = (unsigned short)f2bf(m4.y + p4.y);
    o.z = (unsigned short)f2bf(m4.z + p4.z);
    o.w = (unsigned short)f2bf(m4.w + p4.w);
  } else {
    o.x = o.y = o.z = o.w = 0;
  }
  *(ushort4*)(Abf + idx * 4) = o;
}

// ---------------- vker: v1 -> W2buf col 512 (+zero pad cols), v2, gamma ----------------
__global__ __launch_bounds__(512) void vker(const float* __restrict__ sq_w,
                                            const float* __restrict__ sq_b,
                                            const float* __restrict__ sk_w,
                                            const float* __restrict__ sk_b,
                                            float* __restrict__ W2buf,
                                            float* __restrict__ v2,
                                            float* __restrict__ gbuf){
  int t = threadIdx.x;
  if (blockIdx.x == 0){
    float s = 0.f;
    for (int j = 0; j < 512; ++j) s += sq_w[(long)t * 512 + j] * sk_b[j];
    W2buf[(long)t * W2LD + 512] = s;
    for (int c = 513; c < W2LD; ++c) W2buf[(long)t * W2LD + c] = 0.f;
  } else if (blockIdx.x == 1){
    float s = 0.f;
    for (int j = 0; j < 512; ++j) s += sk_w[(long)t * 512 + j] * sq_b[j];
    v2[t] = s;
  } else {
    if (t == 0){
      float s = 0.f;
      for (int j = 0; j < 512; ++j) s += sq_b[j] * sk_b[j];
      gbuf[0] = s;
    }
  }
}

// ---------------- generic f32 NN GEMM: C = A[M][K] @ B[K][N] * scale ----------------
__global__ __launch_bounds__(256) void gemm_nn(const float* __restrict__ A, int lda,
                                               const float* __restrict__ B, int ldb,
                                               float* __restrict__ C, int ldc,
                                               int K, float scale){
  int tid = threadIdx.x;
  int lane = tid & 63, w = tid >> 6;
  int r0 = blockIdx.x * 16 + w * 4;
  int n  = blockIdx.y * 64 + lane;
  const float* a0 = A + (long)r0 * lda;
  const float* bp = B + n;
  float acc0 = 0.f, acc1 = 0.f, acc2 = 0.f, acc3 = 0.f;
#pragma unroll 2
  for (int k = 0; k < K; k += 4){
    float b0 = bp[(long)k * ldb];
    float b1 = bp[(long)(k + 1) * ldb];
    float b2 = bp[(long)(k + 2) * ldb];
    float b3 = bp[(long)(k + 3) * ldb];
    float4 a;
    a = *(const float4*)(a0 + k);
    acc0 += a.x * b0 + a.y * b1 + a.z * b2 + a.w * b3;
    a = *(const float4*)(a0 + lda + k);
    acc1 += a.x * b0 + a.y * b1 + a.z * b2 + a.w * b3;
    a = *(const float4*)(a0 + 2 * lda + k);
    acc2 += a.x * b0 + a.y * b1 + a.z * b2 + a.w * b3;
    a = *(const float4*)(a0 + 3 * lda + k);
    acc3 += a.x * b0 + a.y * b1 + a.z * b2 + a.w * b3;
  }
  C[(long)r0 * ldc + n]       = acc0 * scale;
  C[(long)(r0 + 1) * ldc + n] = acc1 * scale;
  C[(long)(r0 + 2) * ldc + n] = acc2 * scale;
  C[(long)(r0 + 3) * ldc + n] = acc3 * scale;
}

// ---------------- summT: summText[b][e][n] (transpose + ones row + zero pad) ----------------
__global__ __launch_bounds__(256) void summt_kernel(const float* __restrict__ summ,
                                                    float* __restrict__ summText){
  long id = (long)blockIdx.x * 256 + threadIdx.x;   // 4*520*640 = 1,331,200
  int b = (int)(id / (STROWS * LGLD));
  int rem = (int)(id - (long)b * STROWS * LGLD);
  int e = rem / LGLD, n = rem % LGLD;
  float v;
  if (e < 512)       v = (n < NCHUNK) ? summ[((long)b * NCHUNK + n) * 512 + e] : 0.f;
  else if (e == 512) v = 1.f;
  else               v = 0.f;
  summText[id] = v;
}

// ---------------- beta: betag[b*640+n] = summ_row . v2 + gamma ----------------
__global__ __launch_bounds__(256) void beta_kernel(const float* __restrict__ summ,
                                                   const float* __restrict__ v2,
                                                   const float* __restrict__ gbuf,
                                                   float* __restrict__ betag){
  int w = threadIdx.x >> 6, lane = threadIdx.x & 63;
  int row = blockIdx.x * 4 + w;          // 0..2499
  const float* r = summ + (long)row * 512;
  float s = 0.f;
#pragma unroll
  for (int c = 0; c < 8; ++c) s += r[lane + 64 * c] * v2[lane + 64 * c];
  for (int d = 32; d >= 1; d >>= 1) s += __shfl_xor(s, d, 64);
  if (lane == 0){
    int b = row / NCHUNK, n = row % NCHUNK;
    betag[b * LGLD + n] = s + gbuf[0];
  }
}

// ---------------- logits (NN form): per batch u_ext[128][520] @ summText[520][640] ----------------
__global__ __launch_bounds__(256) void logits_nn(const float* __restrict__ u_ext,
                                                 const float* __restrict__ summText,
                                                 const float* __restrict__ betag,
                                                 const float* __restrict__ chunkden,
                                                 float* __restrict__ logits){
  int b = blockIdx.z;
  int tid = threadIdx.x;
  int lane = tid & 63, w = tid >> 6;
  int r0 = blockIdx.x * 16 + w * 4;      // i
  int n  = blockIdx.y * 64 + lane;
  const float* a0 = u_ext + ((long)b * QN + r0) * W2LD;
  const float* bp = summText + (long)b * STROWS * LGLD + n;
  float acc0 = 0.f, acc1 = 0.f, acc2 = 0.f, acc3 = 0.f;
#pragma unroll 2
  for (int k = 0; k < STROWS; k += 4){
    float b0 = bp[(long)k * LGLD];
    float b1 = bp[(long)(k + 1) * LGLD];
    float b2 = bp[(long)(k + 2) * LGLD];
    float b3 = bp[(long)(k + 3) * LGLD];
    float4 a;
    a = *(const float4*)(a0 + k);
    acc0 += a.x * b0 + a.y * b1 + a.z * b2 + a.w * b3;
    a = *(const float4*)(a0 + W2LD + k);
    acc1 += a.x * b0 + a.y * b1 + a.z * b2 + a.w * b3;
    a = *(const float4*)(a0 + 2 * W2LD + k);
    acc2 += a.x * b0 + a.y * b1 + a.z * b2 + a.w * b3;
    a = *(const float4*)(a0 + 3 * W2LD + k);
    acc3 += a.x * b0 + a.y * b1 + a.z * b2 + a.w * b3;
  }
  if (n < NCHUNK){
    float bet = betag[b * LGLD + n];
    bool dead = (chunkden[b * NCHUNK + n] <= 0.f);
    float v0 = (acc0 + bet) * LOGIT_SCALE;
    float v1 = (acc1 + bet) * LOGIT_SCALE;
    float v2 = (acc2 + bet) * LOGIT_SCALE;
    float v3 = (acc3 + bet) * LOGIT_SCALE;
    if (dead){ v0 = v1 = v2 = v3 = -FLT_MAX; }
    long base = ((long)b * QN + r0) * LGLD + n;
    logits[base]            = v0;
    logits[base + LGLD]     = v1;
    logits[base + 2 * LGLD] = v2;
    logits[base + 3 * LGLD] = v3;
  }
}

// ---------------- top-8 + softmax weights, one wave per (b,i) row ----------------
__global__ __launch_bounds__(64) void topk_kernel(const float* __restrict__ logits,
                                                  int* __restrict__ topi_out,
                                                  float* __restrict__ wts_out){
  int row = blockIdx.x;   // b*128+i
  __shared__ float lds[NCHUNK];
  __shared__ float topv[TOPKK];
  __shared__ int   topi[TOPKK];
  int lane = threadIdx.x;
  for (int idx = lane; idx < NCHUNK; idx += 64) lds[idx] = logits[(long)row * LGLD + idx];
  __syncthreads();
  for (int it = 0; it < TOPKK; ++it){
    float bv = -INFINITY; int bi = 0x7fffffff;
    for (int idx = lane; idx < NCHUNK; idx += 64){
      float v = lds[idx];
      if (v > bv){ bv = v; bi = idx; }
    }
    for (int d = 32; d >= 1; d >>= 1){
      float ov = __shfl_xor(bv, d, 64);
      int   oi = __shfl_xor(bi, d, 64);
      if (ov > bv || (ov == bv && oi < bi)){ bv = ov; bi = oi; }
    }
    if (lane == 0){ topv[it] = bv; topi[it] = bi; lds[bi] = -INFINITY; }
    __syncthreads();
  }
  if (lane == 0){
    float m = topv[0];
    for (int r = 1; r < TOPKK; ++r) m = fmaxf(m, topv[r]);
    float e[TOPKK], s = 0.f;
    for (int r = 0; r < TOPKK; ++r){ e[r] = expf(topv[r] - m); s += e[r]; }
    for (int r = 0; r < TOPKK; ++r){
      wts_out[(long)row * TOPKK + r] = e[r] / s;
      topi_out[(long)row * TOPKK + r] = topi[r];
    }
  }
}

// ---------------- KV GEMM, 2-phase double-buffered ----------------
__global__ __launch_bounds__(256) void kv_gemm(const unsigned short* __restrict__ A,
                                               const unsigned short* __restrict__ Bt,
                                               unsigned short* __restrict__ kvout){
  __shared__ unsigned short As[2][128 * 32];   // 2 x 8 KB
  __shared__ unsigned short Bs[2][128 * 32];
  int id = blockIdx.x;
  int panel = id >> 3, nb = id & 7;
  int m0 = panel << 7, n0 = nb << 7;
  int tid = threadIdx.x;
  int wid = tid >> 6, lane = tid & 63;
  int wr = wid >> 1, wc = wid & 1;
  int lr = lane & 15, lg = lane >> 4;

  int srow = wid * 16 + (lane >> 2);
  int scol = (lane & 3) << 3;
  const unsigned short* gA0 = A  + (long)(m0 + srow) * 512 + scol;
  const unsigned short* gA1 = gA0 + 64 * 512;
  const unsigned short* gB0 = Bt + (long)(n0 + srow) * 512 + scol;
  const unsigned short* gB1 = gB0 + 64 * 512;
  int lofs0 = (wid * 16) * 32;
  int lofs1 = (64 + wid * 16) * 32;

  f32x4 acc[4][4];
#pragma unroll
  for (int i = 0; i < 4; ++i)
#pragma unroll
    for (int j = 0; j < 4; ++j) acc[i][j] = (f32x4)0.f;

#define STAGE(B, K0) { gload16(gA0 + (K0), &As[B][lofs0]); gload16(gA1 + (K0), &As[B][lofs1]); \
                       gload16(gB0 + (K0), &Bs[B][lofs0]); gload16(gB1 + (K0), &Bs[B][lofs1]); }
#define COMPUTE(B) { bf16x8 af[4], bfv[4]; \
  _Pragma("unroll") for (int mi = 0; mi < 4; ++mi) af[mi]  = *(const bf16x8*)&As[B][(wr * 64 + mi * 16 + lr) * 32 + lg * 8]; \
  _Pragma("unroll") for (int ni = 0; ni < 4; ++ni) bfv[ni] = *(const bf16x8*)&Bs[B][(wc * 64 + ni * 16 + lr) * 32 + lg * 8]; \
  _Pragma("unroll") for (int mi = 0; mi < 4; ++mi) \
    _Pragma("unroll") for (int ni = 0; ni < 4; ++ni) \
      acc[mi][ni] = __builtin_amdgcn_mfma_f32_16x16x32_bf16(af[mi], bfv[ni], acc[mi][ni], 0, 0, 0); }

  STAGE(0, 0);
  __syncthreads();
#pragma unroll 1
  for (int t = 0; t < 16; t += 2){
    if (t + 1 < 16) STAGE(1, (t + 1) * 32);
    COMPUTE(0);
    __syncthreads();
    if (t + 2 < 16) STAGE(0, (t + 2) * 32);
    COMPUTE(1);
    __syncthreads();
  }
#undef STAGE
#undef COMPUTE

#pragma unroll
  for (int mi = 0; mi < 4; ++mi)
#pragma unroll
    for (int ni = 0; ni < 4; ++ni)
#pragma unroll
      for (int rr = 0; rr < 4; ++rr){
        int gr = m0 + wr * 64 + mi * 16 + lg * 4 + rr;
        int gn = n0 + wc * 64 + ni * 16 + lr;
        kvout[(long)gr * NKV + gn] = (unsigned short)f2bf(acc[mi][ni][rr]);
      }
}

// ---------------- attention per (i, k-slot) for one batch ----------------
__global__ __launch_bounds__(256) void attn_kernel(const float* __restrict__ qh,
                                                   const unsigned short* __restrict__ kv,
                                                   const int* __restrict__ topidx,
                                                   const float* __restrict__ wts,
                                                   const void* __restrict__ mask,
                                                   const int* __restrict__ flagp,
                                                   float* __restrict__ osc,
                                                   int bb){
  int bx = blockIdx.x;
  int i = bx >> 3, k = bx & 7;
  int t = threadIdx.x;
  __shared__ float qs[HID];
  __shared__ float att[HEADS][CHUNK + 1];
  long sel = ((long)(bb * QN + i)) * TOPKK + k;
  int chunk = topidx[sel];
  float w8 = wts[sel];
  const float* qrow = qh + ((long)(bb * QN + i)) * HID;
  qs[t] = qrow[t]; qs[t + 256] = qrow[t + 256];
  __syncthreads();
  int flag = *flagp;
  int h = t >> 5, c = t & 31;
  const unsigned short* krow = kv + ((long)(chunk * CHUNK + c)) * NKV + h * DHEAD;
  float s = 0.f;
#pragma unroll
  for (int e8 = 0; e8 < 8; ++e8){
    bf16x8 k8 = *(const bf16x8*)(krow + e8 * 8);
#pragma unroll
    for (int j = 0; j < 8; ++j) s += qs[h * DHEAD + e8 * 8 + j] * bf2f((unsigned short)k8[j]);
  }
  bool mv = mask_at(mask, flag, (long)bb * NMEM + (long)chunk * CHUNK + c);
  if (!mv) s = -FLT_MAX;
  float m = s;
  for (int d = 16; d >= 1; d >>= 1) m = fmaxf(m, __shfl_xor(m, d, 32));
  float p = expf(s - m);
  float su = p;
  for (int d = 16; d >= 1; d >>= 1) su += __shfl_xor(su, d, 32);
  att[h][c] = p / su;
  __syncthreads();
  int e0 = (t & 31) * 2;
  float o0 = 0.f, o1 = 0.f;
#pragma unroll 4
  for (int c2 = 0; c2 < CHUNK; ++c2){
    float a = att[h][c2];
    const unsigned short* vr = kv + ((long)(chunk * CHUNK + c2)) * NKV + 512 + h * DHEAD + e0;
    o0 += a * bf2f(vr[0]);
    o1 += a * bf2f(vr[1]);
  }
  long ob = (((long)(bb * QN + i) * TOPKK) + k) * HID + h * DHEAD + e0;
  osc[ob]     = o0 * w8;
  osc[ob + 1] = o1 * w8;
}

// ---------------- final: reduce over k, then @ (out_w@fc2_w) + folded bias ----------------
__global__ __launch_bounds__(512) void final_kernel(const float* __restrict__ osc,
                                                    const float* __restrict__ Wf,
                                                    const float* __restrict__ bfold,
                                                    float* __restrict__ out){
  int bi = blockIdx.x;   // b*128+i
  int t = threadIdx.x;
  __shared__ float lds[HID];
  float s = 0.f;
  for (int k = 0; k < TOPKK; ++k) s += osc[(((long)bi * TOPKK) + k) * HID + t];
  lds[t] = s;
  __syncthreads();
  if (t < 5){
    float a = bfold[t];
    for (int d = 0; d < HID; ++d) a += lds[d] * Wf[d * 5 + t];
    out[bi * 5 + t] = a;
  }
}

extern "C" void kernel_launch(void* const* d_in, const int* in_sizes, int n_in,
                              void* d_out, int out_size, void* d_ws, size_t ws_size,
                              hipStream_t stream) {
  const float* queries  = (const float*)d_in[1];
  const float* memories = (const float*)d_in[2];
  const void*  mask     = d_in[3];
  const float* sq_w = (const float*)d_in[10];
  const float* sq_b = (const float*)d_in[11];
  const float* sk_w = (const float*)d_in[12];
  const float* sk_b = (const float*)d_in[13];
  const float* q_w  = (const float*)d_in[14];
  const float* kv_w = (const float*)d_in[15];
  const float* out_w = (const float*)d_in[16];
  const float* out_b = (const float*)d_in[17];
  const float* fc2_w = (const float*)d_in[18];
  const float* fc2_b = (const float*)d_in[19];
  float* out = (float*)d_out;

  char* ws = (char*)d_ws;
  size_t o_sum  = 0;                        // 5,120,000
  size_t o_den  = o_sum + 5120000;          // 10,240
  size_t o_pos  = o_den + 10240;            // 65,536
  size_t o_wf   = o_pos + 65536;            // 10,240
  size_t o_bf   = o_wf  + 10240;            // 512
  size_t o_ti   = o_bf  + 512;              // 16,384
  size_t o_wt   = o_ti  + 16384;            // 16,384
  size_t o_flag = o_wt  + 16384;            // 512
  size_t o_qh   = o_flag + 512;             // 1,048,576
  size_t o_w2   = o_qh  + 1048576;          // 1,179,648
  size_t o_uex  = o_w2  + 1179648;          // 1,179,648
  size_t o_st   = o_uex + 1179648;          // 5,324,800
  size_t o_bg   = o_st  + 5324800;          // 10,240
  size_t o_v2   = o_bg  + 10240;            // 2,048
  size_t o_gm   = o_v2  + 2048;             // 512
  size_t o_lg   = o_gm  + 512;              // 1,310,720
  size_t o_osc  = o_lg  + 1310720;          // 8,388,608
  size_t o_skt  = o_osc + 8388608;          // 1,048,576
  size_t o_abf  = o_skt + 1048576;          // abf: fused 82,313,216 / fallback 20,578,304

  const size_t ABF_ONE = (size_t)MPAD * 512 * 2;          // 20,578,304
  const size_t ABF_ALL = ABF_ONE * NB;                    // 82,313,216
  size_t need_fused = o_abf + ABF_ALL + 1048576 + (size_t)MPAD * NKV * 2;
  bool fused = (ws_size >= need_fused);
  size_t abf_bytes = fused ? ABF_ALL : ABF_ONE;
  size_t o_btw = o_abf + abf_bytes;
  size_t o_kv  = o_btw + 1048576;

  float* summ  = (float*)(ws + o_sum);
  float* den   = (float*)(ws + o_den);
  float* pos   = (float*)(ws + o_pos);
  float* Wf    = (float*)(ws + o_wf);
  float* bfold = (float*)(ws + o_bf);
  int*   ti    = (int*)  (ws + o_ti);
  float* wt    = (float*)(ws + o_wt);
  int*   flagp = (int*)  (ws + o_flag);
  float* qh    = (float*)(ws + o_qh);
  float* W2buf = (float*)(ws + o_w2);
  float* u_ext = (float*)(ws + o_uex);
  float* summText = (float*)(ws + o_st);
  float* betag = (float*)(ws + o_bg);
  float* v2    = (float*)(ws + o_v2);
  float* gbuf  = (float*)(ws + o_gm);
  float* logit = (float*)(ws + o_lg);
  float* osc   = (float*)(ws + o_osc);
  float* skwT  = (float*)(ws + o_skt);
  unsigned short* abf   = (unsigned short*)(ws + o_abf);
  unsigned short* btw   = (unsigned short*)(ws + o_btw);
  unsigned short* kvbuf = (unsigned short*)(ws + o_kv);

  misc_kernel<<<dim3(32), dim3(512), 0, stream>>>(pos, flagp, mask);
  fold_kernel<<<dim3(5), dim3(512), 0, stream>>>(out_w, out_b, fc2_w, fc2_b, Wf, bfold);
  wtr_kernel<<<dim3(2048), dim3(256), 0, stream>>>(kv_w, btw);
  skwt_kernel<<<dim3(1024), dim3(256), 0, stream>>>(sk_w, skwT);
  vker<<<dim3(3), dim3(512), 0, stream>>>(sq_w, sq_b, sk_w, sk_b, W2buf, v2, gbuf);

  // single pass over memories: summ + chunkden (+ bf16 A for all batches when ws allows)
  prepsum_kernel<<<dim3(NCHUNK + 1, NB), dim3(256), 0, stream>>>(
      memories, pos, mask, flagp, fused ? abf : nullptr, summ, den);

  // selection path (f32-exact)
  gemm_nn<<<dim3(32, 8), dim3(256), 0, stream>>>(sq_w, 512, skwT, 512, W2buf, W2LD, 512, 1.0f);
  gemm_nn<<<dim3(32, 9), dim3(256), 0, stream>>>(queries, 512, W2buf, W2LD, u_ext, W2LD, 512, 1.0f);
  gemm_nn<<<dim3(32, 8), dim3(256), 0, stream>>>(queries, 512, q_w, 512, qh, 512, 512, 0.125f);
  summt_kernel<<<dim3(5200), dim3(256), 0, stream>>>(summ, summText);
  beta_kernel<<<dim3(625), dim3(256), 0, stream>>>(summ, v2, gbuf, betag);
  logits_nn<<<dim3(8, 10, NB), dim3(256), 0, stream>>>(u_ext, summText, betag, den, logit);
  topk_kernel<<<dim3(NB * QN), dim3(64), 0, stream>>>(logit, ti, wt);

  for (int bb = 0; bb < NB; ++bb){
    const unsigned short* Ab;
    if (fused){
      Ab = abf + (size_t)bb * MPAD * 512;
    } else {
      prep_kernel<<<dim3(10048), dim3(256), 0, stream>>>(memories + (long)bb * NMEM * HID, pos, abf);
      Ab = abf;
    }
    kv_gemm<<<dim3(157 * 8), dim3(256), 0, stream>>>(Ab, btw, kvbuf);
    attn_kernel<<<dim3(QN * TOPKK), dim3(256), 0, stream>>>(qh, kvbuf, ti, wt, mask, flagp, osc, bb);
  }
  final_kernel<<<dim3(NB * QN), dim3(512), 0, stream>>>(osc, Wf, bfold, out);
}

// Round 5
// 442.297 us; speedup vs baseline: 1.4454x; 1.4454x over previous
//
#include <hip/hip_runtime.h>
#include <hip/hip_bf16.h>
#include <float.h>
#include <math.h>

// Problem constants
#define NB      4
#define QN      128
#define HID     512
#define NMEM    20000
#define MPAD    20096    // 157*128
#define NCHUNK  625
#define CHUNK   32
#define HEADS   8
#define DHEAD   64
#define TOPKK   8
#define NKV     1024   // 2*HEADS*DHEAD
#define LOGIT_SCALE 0.044194173824159216f  // 512^-0.5
#define W2LD    576    // W2buf / u_ext leading dim (512 + 1 alpha col + pad)
#define STROWS  520    // summText rows: 512 + ones row + 7 zero rows
#define LGLD    640    // logits leading dim

typedef __attribute__((ext_vector_type(8))) short bf16x8;
typedef __attribute__((ext_vector_type(4))) float f32x4;

__device__ __forceinline__ short f2bf(float f){
  __hip_bfloat16 h = __float2bfloat16(f);
  return *reinterpret_cast<short*>(&h);
}
__device__ __forceinline__ float bf2f(unsigned short s){
  __hip_bfloat16 h;
  *reinterpret_cast<unsigned short*>(&h) = s;
  return __bfloat162float(h);
}
__device__ __forceinline__ bool mask_at(const void* m, int flag, long i){
  return flag ? (((const unsigned char*)m)[i] != 0)
              : (((const int*)m)[i] != 0);
}
__device__ __forceinline__ void gload16(const void* g, void* l){
  __builtin_amdgcn_global_load_lds((const __attribute__((address_space(1))) void*)g,
                                   (__attribute__((address_space(3))) void*)l, 16, 0, 0);
}

// ---------------- setup: wtr + skwt + misc(pos/flag) + fold + vker, one launch ----------------
// grid 3151 x 256:
//   [0,2048)      wtr:  Bt[1024][512] bf16 = kv_w^T
//   [2048,3072)   skwt: skwT[j][e] = sk_w[e][j]
//   [3072,3136)   misc: pos table (64 blocks of 256) + mask flag
//   [3136,3146)   fold: Wf = out_w @ fc2_w (+ folded bias)
//   [3146,3151)   vker: v1 -> W2buf col512 (+pad), v2, gamma
__global__ __launch_bounds__(256) void setup_kernel(const float* __restrict__ kvw,
                                                    const float* __restrict__ skw,
                                                    const void* __restrict__ mask,
                                                    const float* __restrict__ out_w,
                                                    const float* __restrict__ out_b,
                                                    const float* __restrict__ fc2_w,
                                                    const float* __restrict__ fc2_b,
                                                    const float* __restrict__ sq_w,
                                                    const float* __restrict__ sq_b,
                                                    const float* __restrict__ sk_b,
                                                    unsigned short* __restrict__ Bt,
                                                    float* __restrict__ skwT,
                                                    float* __restrict__ pos,
                                                    int* __restrict__ flagp,
                                                    float* __restrict__ Wf,
                                                    float* __restrict__ bfold,
                                                    float* __restrict__ W2buf,
                                                    float* __restrict__ v2,
                                                    float* __restrict__ gbuf){
  int sub = blockIdx.x;
  int t = threadIdx.x;
  if (sub < 2048){
    long id = (long)sub * 256 + t;
    int n = (int)(id >> 9), k = (int)(id & 511);
    Bt[id] = (unsigned short)f2bf(kvw[(long)k * NKV + n]);
  } else if (sub < 3072){
    long id = (long)(sub - 2048) * 256 + t;
    int e = (int)(id >> 9), j = (int)(id & 511);
    skwT[(long)j * 512 + e] = skw[id];
  } else if (sub < 3136){
    int s = sub - 3072;            // 0..63
    int c = s >> 1;                // 0..31
    int d = (s & 1) * 256 + t;     // 0..511
    int j = (d < 256) ? d : d - 256;
    float invf = expf(-((2.0f * (float)j) / 512.0f) * 9.2103403719761836f);
    float arg = (float)(31 - c) * invf;
    pos[c * 512 + d] = (d < 256) ? sinf(arg) : cosf(arg);
    if (s == 0 && t == 0){
      const unsigned char* mb = (const unsigned char*)mask;
      *flagp = (mb[1] != 0) ? 1 : 0;
    }
  } else if (sub < 3146){
    int s = sub - 3136;            // 0..9
    int j = s >> 1;                // 0..4
    int d = (s & 1) * 256 + t;
    float acc = 0.f;
    for (int k = 0; k < 512; ++k) acc += out_w[(long)d * 512 + k] * fc2_w[k * 5 + j];
    Wf[d * 5 + j] = acc;
    if (d == 0){
      float sb = 0.f;
      for (int k = 0; k < 512; ++k) sb += out_b[k] * fc2_w[k * 5 + j];
      bfold[j] = sb + fc2_b[j];
    }
  } else {
    int s = sub - 3146;            // 0..4
    if (s < 2){
      int d = s * 256 + t;
      float acc = 0.f;
      for (int j = 0; j < 512; ++j) acc += sq_w[(long)d * 512 + j] * sk_b[j];
      W2buf[(long)d * W2LD + 512] = acc;
      for (int c = 513; c < W2LD; ++c) W2buf[(long)d * W2LD + c] = 0.f;
    } else if (s < 4){
      int e = (s - 2) * 256 + t;
      float acc = 0.f;
      for (int j = 0; j < 512; ++j) acc += skw[(long)e * 512 + j] * sq_b[j];
      v2[e] = acc;
    } else {
      __shared__ float g[256];
      g[t] = sq_b[t] * sk_b[t] + sq_b[t + 256] * sk_b[t + 256];
      __syncthreads();
      for (int d = 128; d >= 1; d >>= 1){
        if (t < d) g[t] += g[t + d];
        __syncthreads();
      }
      if (t == 0) gbuf[0] = g[0];
    }
  }
}

// ---------------- fused: memories -> summ + chunkden + bf16 (mem+pos), 512 thr ----------------
__global__ __launch_bounds__(512) void prepsum_kernel(const float* __restrict__ memories,
                                                      const float* __restrict__ pos,
                                                      const void* __restrict__ mask,
                                                      const int* __restrict__ flagp,
                                                      unsigned short* __restrict__ abf_all,
                                                      float* __restrict__ summ,
                                                      float* __restrict__ chunkden){
  int n = blockIdx.x, b = blockIdx.y;
  int t = threadIdx.x;
  unsigned short* abf = abf_all ? abf_all + (long)b * MPAD * 512 : nullptr;
  if (n == NCHUNK){
    if (abf){
      for (int idx = t; idx < 96 * 128; idx += 512){
        ushort4 z = {0, 0, 0, 0};
        *(ushort4*)(abf + (long)(NMEM + (idx >> 7)) * 512 + (long)(idx & 127) * 4) = z;
      }
    }
    return;
  }
  int flag = *flagp;
  long mbase = (long)b * NMEM + (long)n * CHUNK;
  unsigned int m32 = 0;
  for (int c = 0; c < 32; ++c) m32 |= (mask_at(mask, flag, mbase + c) ? 1u : 0u) << c;
  float den = (float)__popc(m32);
  int c4 = t & 127;
  int rh = t >> 7;               // 0..3
  const float* base = memories + mbase * HID;
  float4 acc = {0.f, 0.f, 0.f, 0.f};
#pragma unroll
  for (int c = rh; c < 32; c += 4){
    float4 v  = *(const float4*)(base + (long)c * HID + c4 * 4);
    if (abf){
      float4 p4 = *(const float4*)(pos + c * HID + c4 * 4);
      ushort4 o;
      o.x = (unsigned short)f2bf(v.x + p4.x);
      o.y = (unsigned short)f2bf(v.y + p4.y);
      o.z = (unsigned short)f2bf(v.z + p4.z);
      o.w = (unsigned short)f2bf(v.w + p4.w);
      *(ushort4*)(abf + (long)(n * CHUNK + c) * 512 + c4 * 4) = o;
    }
    if (m32 & (1u << c)){
      acc.x += v.x; acc.y += v.y; acc.z += v.z; acc.w += v.w;
    }
  }
  __shared__ float4 red[512];
  red[t] = acc;
  __syncthreads();
  if (rh == 0){
    float4 a0 = red[t], a1 = red[t + 128], a2 = red[t + 256], a3 = red[t + 384];
    float dv = den + 1e-5f;
    float4 s4;
    s4.x = (a0.x + a1.x + a2.x + a3.x) / dv;
    s4.y = (a0.y + a1.y + a2.y + a3.y) / dv;
    s4.z = (a0.z + a1.z + a2.z + a3.z) / dv;
    s4.w = (a0.w + a1.w + a2.w + a3.w) / dv;
    *(float4*)(summ + ((long)b * NCHUNK + n) * 512 + c4 * 4) = s4;
    if (t == 0) chunkden[b * NCHUNK + n] = den;
  }
}

// ---------------- prep (fallback): (mem+pos) -> bf16 A[MPAD][512] ----------------
__global__ __launch_bounds__(256) void prep_kernel(const float* __restrict__ mem,
                                                   const float* __restrict__ pos,
                                                   unsigned short* __restrict__ Abf){
  long idx = (long)blockIdx.x * 256 + threadIdx.x;
  int r = (int)(idx >> 7);
  int cv = (int)(idx & 127) << 2;
  ushort4 o;
  if (r < NMEM){
    float4 m4 = *(const float4*)(mem + (long)r * 512 + cv);
    float4 p4 = *(const float4*)(pos + (r & 31) * 512 + cv);
    o.x = (unsigned short)f2bf(m4.x + p4.x);
    o.y = (unsigned short)f2bf(m4.y + p4.y);
    o.z = (unsigned short)f2bf(m4.z + p4.z);
    o.w = (unsigned short)f2bf(m4.w + p4.w);
  } else {
    o.x = o.y = o.z = o.w = 0;
  }
  *(ushort4*)(Abf + idx * 4) = o;
}

// ---------------- generic f32 NN GEMM: C = A[M][K] @ B[K][N] * scale ----------------
__global__ __launch_bounds__(256) void gemm_nn(const float* __restrict__ A, int lda,
                                               const float* __restrict__ B, int ldb,
                                               float* __restrict__ C, int ldc,
                                               int K, float scale){
  int tid = threadIdx.x;
  int lane = tid & 63, w = tid >> 6;
  int r0 = blockIdx.x * 16 + w * 4;
  int n  = blockIdx.y * 64 + lane;
  const float* a0 = A + (long)r0 * lda;
  const float* bp = B + n;
  float acc0 = 0.f, acc1 = 0.f, acc2 = 0.f, acc3 = 0.f;
#pragma unroll 2
  for (int k = 0; k < K; k += 4){
    float b0 = bp[(long)k * ldb];
    float b1 = bp[(long)(k + 1) * ldb];
    float b2 = bp[(long)(k + 2) * ldb];
    float b3 = bp[(long)(k + 3) * ldb];
    float4 a;
    a = *(const float4*)(a0 + k);
    acc0 += a.x * b0 + a.y * b1 + a.z * b2 + a.w * b3;
    a = *(const float4*)(a0 + lda + k);
    acc1 += a.x * b0 + a.y * b1 + a.z * b2 + a.w * b3;
    a = *(const float4*)(a0 + 2 * lda + k);
    acc2 += a.x * b0 + a.y * b1 + a.z * b2 + a.w * b3;
    a = *(const float4*)(a0 + 3 * lda + k);
    acc3 += a.x * b0 + a.y * b1 + a.z * b2 + a.w * b3;
  }
  C[(long)r0 * ldc + n]       = acc0 * scale;
  C[(long)(r0 + 1) * ldc + n] = acc1 * scale;
  C[(long)(r0 + 2) * ldc + n] = acc2 * scale;
  C[(long)(r0 + 3) * ldc + n] = acc3 * scale;
}

// ---------------- uq: u_ext = queries@W2buf (y<9) and qh = queries@q_w*0.125 (y>=9) ----------------
__global__ __launch_bounds__(256) void uq_kernel(const float* __restrict__ queries,
                                                 const float* __restrict__ W2buf,
                                                 const float* __restrict__ q_w,
                                                 float* __restrict__ u_ext,
                                                 float* __restrict__ qh){
  int y = blockIdx.y;
  const float* B; int ldb; float* C; int ldc; int nbase; float scale;
  if (y < 9){ B = W2buf; ldb = W2LD; C = u_ext; ldc = W2LD; nbase = y * 64; scale = 1.0f; }
  else      { B = q_w;   ldb = 512;  C = qh;    ldc = 512;  nbase = (y - 9) * 64; scale = 0.125f; }
  int tid = threadIdx.x;
  int lane = tid & 63, w = tid >> 6;
  int r0 = blockIdx.x * 16 + w * 4;
  int n  = nbase + lane;
  const float* a0 = queries + (long)r0 * 512;
  const float* bp = B + n;
  float acc0 = 0.f, acc1 = 0.f, acc2 = 0.f, acc3 = 0.f;
#pragma unroll 2
  for (int k = 0; k < 512; k += 4){
    float b0 = bp[(long)k * ldb];
    float b1 = bp[(long)(k + 1) * ldb];
    float b2 = bp[(long)(k + 2) * ldb];
    float b3 = bp[(long)(k + 3) * ldb];
    float4 a;
    a = *(const float4*)(a0 + k);
    acc0 += a.x * b0 + a.y * b1 + a.z * b2 + a.w * b3;
    a = *(const float4*)(a0 + 512 + k);
    acc1 += a.x * b0 + a.y * b1 + a.z * b2 + a.w * b3;
    a = *(const float4*)(a0 + 1024 + k);
    acc2 += a.x * b0 + a.y * b1 + a.z * b2 + a.w * b3;
    a = *(const float4*)(a0 + 1536 + k);
    acc3 += a.x * b0 + a.y * b1 + a.z * b2 + a.w * b3;
  }
  C[(long)r0 * ldc + n]       = acc0 * scale;
  C[(long)(r0 + 1) * ldc + n] = acc1 * scale;
  C[(long)(r0 + 2) * ldc + n] = acc2 * scale;
  C[(long)(r0 + 3) * ldc + n] = acc3 * scale;
}

// ---------------- summT: summText[b][e][n] (transpose + ones row + zero pad) ----------------
__global__ __launch_bounds__(256) void summt_kernel(const float* __restrict__ summ,
                                                    float* __restrict__ summText){
  long id = (long)blockIdx.x * 256 + threadIdx.x;   // 4*520*640 = 1,331,200
  int b = (int)(id / (STROWS * LGLD));
  int rem = (int)(id - (long)b * STROWS * LGLD);
  int e = rem / LGLD, n = rem % LGLD;
  float v;
  if (e < 512)       v = (n < NCHUNK) ? summ[((long)b * NCHUNK + n) * 512 + e] : 0.f;
  else if (e == 512) v = 1.f;
  else               v = 0.f;
  summText[id] = v;
}

// ---------------- beta: betag[b*640+n] = summ_row . v2 + gamma ----------------
__global__ __launch_bounds__(256) void beta_kernel(const float* __restrict__ summ,
                                                   const float* __restrict__ v2,
                                                   const float* __restrict__ gbuf,
                                                   float* __restrict__ betag){
  int w = threadIdx.x >> 6, lane = threadIdx.x & 63;
  int row = blockIdx.x * 4 + w;          // 0..2499
  const float* r = summ + (long)row * 512;
  float s = 0.f;
#pragma unroll
  for (int c = 0; c < 8; ++c) s += r[lane + 64 * c] * v2[lane + 64 * c];
  for (int d = 32; d >= 1; d >>= 1) s += __shfl_xor(s, d, 64);
  if (lane == 0){
    int b = row / NCHUNK, n = row % NCHUNK;
    betag[b * LGLD + n] = s + gbuf[0];
  }
}

// ---------------- logits (NN form): per batch u_ext[128][520] @ summText[520][640] ----------------
__global__ __launch_bounds__(256) void logits_nn(const float* __restrict__ u_ext,
                                                 const float* __restrict__ summText,
                                                 const float* __restrict__ betag,
                                                 const float* __restrict__ chunkden,
                                                 float* __restrict__ logits){
  int b = blockIdx.z;
  int tid = threadIdx.x;
  int lane = tid & 63, w = tid >> 6;
  int r0 = blockIdx.x * 16 + w * 4;      // i
  int n  = blockIdx.y * 64 + lane;
  const float* a0 = u_ext + ((long)b * QN + r0) * W2LD;
  const float* bp = summText + (long)b * STROWS * LGLD + n;
  float acc0 = 0.f, acc1 = 0.f, acc2 = 0.f, acc3 = 0.f;
#pragma unroll 2
  for (int k = 0; k < STROWS; k += 4){
    float b0 = bp[(long)k * LGLD];
    float b1 = bp[(long)(k + 1) * LGLD];
    float b2 = bp[(long)(k + 2) * LGLD];
    float b3 = bp[(long)(k + 3) * LGLD];
    float4 a;
    a = *(const float4*)(a0 + k);
    acc0 += a.x * b0 + a.y * b1 + a.z * b2 + a.w * b3;
    a = *(const float4*)(a0 + W2LD + k);
    acc1 += a.x * b0 + a.y * b1 + a.z * b2 + a.w * b3;
    a = *(const float4*)(a0 + 2 * W2LD + k);
    acc2 += a.x * b0 + a.y * b1 + a.z * b2 + a.w * b3;
    a = *(const float4*)(a0 + 3 * W2LD + k);
    acc3 += a.x * b0 + a.y * b1 + a.z * b2 + a.w * b3;
  }
  if (n < NCHUNK){
    float bet = betag[b * LGLD + n];
    bool dead = (chunkden[b * NCHUNK + n] <= 0.f);
    float v0 = (acc0 + bet) * LOGIT_SCALE;
    float v1 = (acc1 + bet) * LOGIT_SCALE;
    float v2 = (acc2 + bet) * LOGIT_SCALE;
    float v3 = (acc3 + bet) * LOGIT_SCALE;
    if (dead){ v0 = v1 = v2 = v3 = -FLT_MAX; }
    long base = ((long)b * QN + r0) * LGLD + n;
    logits[base]            = v0;
    logits[base + LGLD]     = v1;
    logits[base + 2 * LGLD] = v2;
    logits[base + 3 * LGLD] = v3;
  }
}

// ---------------- top-8 + softmax weights, one wave per (b,i) row ----------------
__global__ __launch_bounds__(64) void topk_kernel(const float* __restrict__ logits,
                                                  int* __restrict__ topi_out,
                                                  float* __restrict__ wts_out){
  int row = blockIdx.x;   // b*128+i
  __shared__ float lds[NCHUNK];
  __shared__ float topv[TOPKK];
  __shared__ int   topi[TOPKK];
  int lane = threadIdx.x;
  for (int idx = lane; idx < NCHUNK; idx += 64) lds[idx] = logits[(long)row * LGLD + idx];
  __syncthreads();
  for (int it = 0; it < TOPKK; ++it){
    float bv = -INFINITY; int bi = 0x7fffffff;
    for (int idx = lane; idx < NCHUNK; idx += 64){
      float v = lds[idx];
      if (v > bv){ bv = v; bi = idx; }
    }
    for (int d = 32; d >= 1; d >>= 1){
      float ov = __shfl_xor(bv, d, 64);
      int   oi = __shfl_xor(bi, d, 64);
      if (ov > bv || (ov == bv && oi < bi)){ bv = ov; bi = oi; }
    }
    if (lane == 0){ topv[it] = bv; topi[it] = bi; lds[bi] = -INFINITY; }
    __syncthreads();
  }
  if (lane == 0){
    float m = topv[0];
    for (int r = 1; r < TOPKK; ++r) m = fmaxf(m, topv[r]);
    float e[TOPKK], s = 0.f;
    for (int r = 0; r < TOPKK; ++r){ e[r] = expf(topv[r] - m); s += e[r]; }
    for (int r = 0; r < TOPKK; ++r){
      wts_out[(long)row * TOPKK + r] = e[r] / s;
      topi_out[(long)row * TOPKK + r] = topi[r];
    }
  }
}

// ---------------- KV GEMM, dbuf, XCD-aware remap, multi-batch ----------------
// Launch grid = ceil(nbatch*157/8)*64 blocks.
// Remap: panel = (L>>6)*8 + (L&7), nb = (L>>3)&7  => XCD(L%8) == panel%8,
// so the 8 blocks sharing an A-panel land on one XCD (A fetched once per panel).
__global__ __launch_bounds__(256) void kv_gemm(const unsigned short* __restrict__ A_all,
                                               const unsigned short* __restrict__ Bt,
                                               unsigned short* __restrict__ kv_all,
                                               int npanels){
  int L = blockIdx.x;
  int panel = ((L >> 6) << 3) | (L & 7);
  int nb = (L >> 3) & 7;
  if (panel >= npanels) return;
  int bb = panel / 157;
  int p  = panel - bb * 157;
  const unsigned short* A = A_all + (size_t)bb * MPAD * 512;
  unsigned short* kvout   = kv_all + (size_t)bb * MPAD * NKV;

  __shared__ unsigned short As[2][128 * 32];
  __shared__ unsigned short Bs[2][128 * 32];
  int m0 = p << 7, n0 = nb << 7;
  int tid = threadIdx.x;
  int wid = tid >> 6, lane = tid & 63;
  int wr = wid >> 1, wc = wid & 1;
  int lr = lane & 15, lg = lane >> 4;

  int srow = wid * 16 + (lane >> 2);
  int scol = (lane & 3) << 3;
  const unsigned short* gA0 = A  + (long)(m0 + srow) * 512 + scol;
  const unsigned short* gA1 = gA0 + 64 * 512;
  const unsigned short* gB0 = Bt + (long)(n0 + srow) * 512 + scol;
  const unsigned short* gB1 = gB0 + 64 * 512;
  int lofs0 = (wid * 16) * 32;
  int lofs1 = (64 + wid * 16) * 32;

  f32x4 acc[4][4];
#pragma unroll
  for (int i = 0; i < 4; ++i)
#pragma unroll
    for (int j = 0; j < 4; ++j) acc[i][j] = (f32x4)0.f;

#define STAGE(B, K0) { gload16(gA0 + (K0), &As[B][lofs0]); gload16(gA1 + (K0), &As[B][lofs1]); \
                       gload16(gB0 + (K0), &Bs[B][lofs0]); gload16(gB1 + (K0), &Bs[B][lofs1]); }
#define COMPUTE(B) { bf16x8 af[4], bfv[4]; \
  _Pragma("unroll") for (int mi = 0; mi < 4; ++mi) af[mi]  = *(const bf16x8*)&As[B][(wr * 64 + mi * 16 + lr) * 32 + lg * 8]; \
  _Pragma("unroll") for (int ni = 0; ni < 4; ++ni) bfv[ni] = *(const bf16x8*)&Bs[B][(wc * 64 + ni * 16 + lr) * 32 + lg * 8]; \
  _Pragma("unroll") for (int mi = 0; mi < 4; ++mi) \
    _Pragma("unroll") for (int ni = 0; ni < 4; ++ni) \
      acc[mi][ni] = __builtin_amdgcn_mfma_f32_16x16x32_bf16(af[mi], bfv[ni], acc[mi][ni], 0, 0, 0); }

  STAGE(0, 0);
  __syncthreads();
#pragma unroll 1
  for (int t = 0; t < 16; t += 2){
    if (t + 1 < 16) STAGE(1, (t + 1) * 32);
    COMPUTE(0);
    __syncthreads();
    if (t + 2 < 16) STAGE(0, (t + 2) * 32);
    COMPUTE(1);
    __syncthreads();
  }
#undef STAGE
#undef COMPUTE

#pragma unroll
  for (int mi = 0; mi < 4; ++mi)
#pragma unroll
    for (int ni = 0; ni < 4; ++ni)
#pragma unroll
      for (int rr = 0; rr < 4; ++rr){
        int gr = m0 + wr * 64 + mi * 16 + lg * 4 + rr;
        int gn = n0 + wc * 64 + ni * 16 + lr;
        kvout[(long)gr * NKV + gn] = (unsigned short)f2bf(acc[mi][ni][rr]);
      }
}

// ---------------- attention; bb_arg<0 => batched (grid 4096, per-batch kv stride) ----------------
__global__ __launch_bounds__(256) void attn_kernel(const float* __restrict__ qh,
                                                   const unsigned short* __restrict__ kv,
                                                   const int* __restrict__ topidx,
                                                   const float* __restrict__ wts,
                                                   const void* __restrict__ mask,
                                                   const int* __restrict__ flagp,
                                                   float* __restrict__ osc,
                                                   int bb_arg){
  int bx = blockIdx.x;
  int bb, rem;
  const unsigned short* kvb;
  if (bb_arg < 0){
    bb = bx >> 10; rem = bx & 1023;
    kvb = kv + (size_t)bb * MPAD * NKV;
  } else {
    bb = bb_arg; rem = bx;
    kvb = kv;
  }
  int i = rem >> 3, k = rem & 7;
  int t = threadIdx.x;
  __shared__ float qs[HID];
  __shared__ float att[HEADS][CHUNK + 1];
  long sel = ((long)(bb * QN + i)) * TOPKK + k;
  int chunk = topidx[sel];
  float w8 = wts[sel];
  const float* qrow = qh + ((long)(bb * QN + i)) * HID;
  qs[t] = qrow[t]; qs[t + 256] = qrow[t + 256];
  __syncthreads();
  int flag = *flagp;
  int h = t >> 5, c = t & 31;
  const unsigned short* krow = kvb + ((long)(chunk * CHUNK + c)) * NKV + h * DHEAD;
  float s = 0.f;
#pragma unroll
  for (int e8 = 0; e8 < 8; ++e8){
    bf16x8 k8 = *(const bf16x8*)(krow + e8 * 8);
#pragma unroll
    for (int j = 0; j < 8; ++j) s += qs[h * DHEAD + e8 * 8 + j] * bf2f((unsigned short)k8[j]);
  }
  bool mv = mask_at(mask, flag, (long)bb * NMEM + (long)chunk * CHUNK + c);
  if (!mv) s = -FLT_MAX;
  float m = s;
  for (int d = 16; d >= 1; d >>= 1) m = fmaxf(m, __shfl_xor(m, d, 32));
  float p = expf(s - m);
  float su = p;
  for (int d = 16; d >= 1; d >>= 1) su += __shfl_xor(su, d, 32);
  att[h][c] = p / su;
  __syncthreads();
  int e0 = (t & 31) * 2;
  float o0 = 0.f, o1 = 0.f;
#pragma unroll 4
  for (int c2 = 0; c2 < CHUNK; ++c2){
    float a = att[h][c2];
    const unsigned short* vr = kvb + ((long)(chunk * CHUNK + c2)) * NKV + 512 + h * DHEAD + e0;
    o0 += a * bf2f(vr[0]);
    o1 += a * bf2f(vr[1]);
  }
  long ob = (((long)(bb * QN + i) * TOPKK) + k) * HID + h * DHEAD + e0;
  osc[ob]     = o0 * w8;
  osc[ob + 1] = o1 * w8;
}

// ---------------- final: reduce over k, then @ (out_w@fc2_w) + folded bias ----------------
__global__ __launch_bounds__(512) void final_kernel(const float* __restrict__ osc,
                                                    const float* __restrict__ Wf,
                                                    const float* __restrict__ bfold,
                                                    float* __restrict__ out){
  int bi = blockIdx.x;   // b*128+i
  int t = threadIdx.x;
  __shared__ float lds[HID];
  float s = 0.f;
  for (int k = 0; k < TOPKK; ++k) s += osc[(((long)bi * TOPKK) + k) * HID + t];
  lds[t] = s;
  __syncthreads();
  int w = t >> 6, lane = t & 63;
  if (w < 5){
    float a = 0.f;
#pragma unroll
    for (int c = 0; c < 8; ++c) a += lds[lane + 64 * c] * Wf[(lane + 64 * c) * 5 + w];
    for (int d = 32; d >= 1; d >>= 1) a += __shfl_xor(a, d, 64);
    if (lane == 0) out[bi * 5 + w] = a + bfold[w];
  }
}

extern "C" void kernel_launch(void* const* d_in, const int* in_sizes, int n_in,
                              void* d_out, int out_size, void* d_ws, size_t ws_size,
                              hipStream_t stream) {
  const float* queries  = (const float*)d_in[1];
  const float* memories = (const float*)d_in[2];
  const void*  mask     = d_in[3];
  const float* sq_w = (const float*)d_in[10];
  const float* sq_b = (const float*)d_in[11];
  const float* sk_w = (const float*)d_in[12];
  const float* sk_b = (const float*)d_in[13];
  const float* q_w  = (const float*)d_in[14];
  const float* kv_w = (const float*)d_in[15];
  const float* out_w = (const float*)d_in[16];
  const float* out_b = (const float*)d_in[17];
  const float* fc2_w = (const float*)d_in[18];
  const float* fc2_b = (const float*)d_in[19];
  float* out = (float*)d_out;

  char* ws = (char*)d_ws;
  size_t o_sum  = 0;                        // 5,120,000
  size_t o_den  = o_sum + 5120000;          // 10,240
  size_t o_pos  = o_den + 10240;            // 65,536
  size_t o_wf   = o_pos + 65536;            // 10,240
  size_t o_bf   = o_wf  + 10240;            // 512
  size_t o_ti   = o_bf  + 512;              // 16,384
  size_t o_wt   = o_ti  + 16384;            // 16,384
  size_t o_flag = o_wt  + 16384;            // 512
  size_t o_qh   = o_flag + 512;             // 1,048,576
  size_t o_w2   = o_qh  + 1048576;          // 1,179,648
  size_t o_uex  = o_w2  + 1179648;          // 1,179,648
  size_t o_st   = o_uex + 1179648;          // 5,324,800
  size_t o_bg   = o_st  + 5324800;          // 10,240
  size_t o_v2   = o_bg  + 10240;            // 2,048
  size_t o_gm   = o_v2  + 2048;             // 512
  size_t o_lg   = o_gm  + 512;              // 1,310,720
  size_t o_osc  = o_lg  + 1310720;          // 8,388,608
  size_t o_skt  = o_osc + 8388608;          // 1,048,576
  size_t o_abf  = o_skt + 1048576;

  const size_t ABF_ONE = (size_t)MPAD * 512 * 2;          // 20,578,304
  const size_t ABF_ALL = ABF_ONE * NB;                    // 82,313,216
  const size_t KV_ONE  = (size_t)MPAD * NKV * 2;          // 41,156,608
  size_t need_fused   = o_abf + ABF_ALL + 1048576 + KV_ONE;
  size_t need_batched = o_abf + ABF_ALL + 1048576 + KV_ONE * NB;
  bool fused   = (ws_size >= need_fused);
  bool batched = (ws_size >= need_batched);
  size_t abf_bytes = fused ? ABF_ALL : ABF_ONE;
  size_t o_btw = o_abf + abf_bytes;
  size_t o_kv  = o_btw + 1048576;

  float* summ  = (float*)(ws + o_sum);
  float* den   = (float*)(ws + o_den);
  float* pos   = (float*)(ws + o_pos);
  float* Wf    = (float*)(ws + o_wf);
  float* bfold = (float*)(ws + o_bf);
  int*   ti    = (int*)  (ws + o_ti);
  float* wt    = (float*)(ws + o_wt);
  int*   flagp = (int*)  (ws + o_flag);
  float* qh    = (float*)(ws + o_qh);
  float* W2buf = (float*)(ws + o_w2);
  float* u_ext = (float*)(ws + o_uex);
  float* summText = (float*)(ws + o_st);
  float* betag = (float*)(ws + o_bg);
  float* v2    = (float*)(ws + o_v2);
  float* gbuf  = (float*)(ws + o_gm);
  float* logit = (float*)(ws + o_lg);
  float* osc   = (float*)(ws + o_osc);
  float* skwT  = (float*)(ws + o_skt);
  unsigned short* abf   = (unsigned short*)(ws + o_abf);
  unsigned short* btw   = (unsigned short*)(ws + o_btw);
  unsigned short* kvbuf = (unsigned short*)(ws + o_kv);

  // one setup launch: wtr + skwt + pos/flag + fold + vker
  setup_kernel<<<dim3(3151), dim3(256), 0, stream>>>(
      kv_w, sk_w, mask, out_w, out_b, fc2_w, fc2_b, sq_w, sq_b, sk_b,
      btw, skwT, pos, flagp, Wf, bfold, W2buf, v2, gbuf);

  // single pass over memories: summ + chunkden (+ bf16 A for all batches when ws allows)
  prepsum_kernel<<<dim3(NCHUNK + 1, NB), dim3(512), 0, stream>>>(
      memories, pos, mask, flagp, fused ? abf : nullptr, summ, den);

  // selection path (f32-exact)
  gemm_nn<<<dim3(32, 8), dim3(256), 0, stream>>>(sq_w, 512, skwT, 512, W2buf, W2LD, 512, 1.0f);
  uq_kernel<<<dim3(32, 17), dim3(256), 0, stream>>>(queries, W2buf, q_w, u_ext, qh);
  summt_kernel<<<dim3(5200), dim3(256), 0, stream>>>(summ, summText);
  beta_kernel<<<dim3(625), dim3(256), 0, stream>>>(summ, v2, gbuf, betag);
  logits_nn<<<dim3(8, 10, NB), dim3(256), 0, stream>>>(u_ext, summText, betag, den, logit);
  topk_kernel<<<dim3(NB * QN), dim3(64), 0, stream>>>(logit, ti, wt);

  if (batched){
    // all 4 batches in one kv GEMM launch, then one attention launch
    kv_gemm<<<dim3(((NB * 157 + 7) / 8) * 64), dim3(256), 0, stream>>>(abf, btw, kvbuf, NB * 157);
    attn_kernel<<<dim3(NB * QN * TOPKK), dim3(256), 0, stream>>>(qh, kvbuf, ti, wt, mask, flagp, osc, -1);
  } else {
    for (int bb = 0; bb < NB; ++bb){
      const unsigned short* Ab;
      if (fused){
        Ab = abf + (size_t)bb * MPAD * 512;
      } else {
        prep_kernel<<<dim3(10048), dim3(256), 0, stream>>>(memories + (long)bb * NMEM * HID, pos, abf);
        Ab = abf;
      }
      kv_gemm<<<dim3(((157 + 7) / 8) * 64), dim3(256), 0, stream>>>(Ab, btw, kvbuf, 157);
      attn_kernel<<<dim3(QN * TOPKK), dim3(256), 0, stream>>>(qh, kvbuf, ti, wt, mask, flagp, osc, bb);
    }
  }
  final_kernel<<<dim3(NB * QN), dim3(512), 0, stream>>>(osc, Wf, bfold, out);
}

// Round 6
// 423.550 us; speedup vs baseline: 1.5094x; 1.0443x over previous
//
#include <hip/hip_runtime.h>
#include <hip/hip_bf16.h>
#include <float.h>
#include <math.h>

// Problem constants
#define NB      4
#define QN      128
#define HID     512
#define NMEM    20000
#define MPAD    20096    // 157*128
#define NCHUNK  625
#define CHUNK   32
#define HEADS   8
#define DHEAD   64
#define TOPKK   8
#define NKV     1024   // 2*HEADS*DHEAD
#define LOGIT_SCALE 0.044194173824159216f  // 512^-0.5
#define W2LD    576    // W2buf / u_ext leading dim (512 + 1 alpha col + pad)
#define STROWS  520    // summText rows: 512 + ones row + 7 zero rows
#define LGLD    640    // logits leading dim

typedef __attribute__((ext_vector_type(8))) short bf16x8;
typedef __attribute__((ext_vector_type(4))) float f32x4;

__device__ __forceinline__ short f2bf(float f){
  __hip_bfloat16 h = __float2bfloat16(f);
  return *reinterpret_cast<short*>(&h);
}
__device__ __forceinline__ float bf2f(unsigned short s){
  __hip_bfloat16 h;
  *reinterpret_cast<unsigned short*>(&h) = s;
  return __bfloat162float(h);
}
__device__ __forceinline__ bool mask_at(const void* m, int flag, long i){
  return flag ? (((const unsigned char*)m)[i] != 0)
              : (((const int*)m)[i] != 0);
}
__device__ __forceinline__ void gload16(const void* g, void* l){
  __builtin_amdgcn_global_load_lds((const __attribute__((address_space(1))) void*)g,
                                   (__attribute__((address_space(3))) void*)l, 16, 0, 0);
}

// ---------------- setup: wtr + skwt + misc(pos/flag) + fold + vker, one launch ----------------
__global__ __launch_bounds__(256) void setup_kernel(const float* __restrict__ kvw,
                                                    const float* __restrict__ skw,
                                                    const void* __restrict__ mask,
                                                    const float* __restrict__ out_w,
                                                    const float* __restrict__ out_b,
                                                    const float* __restrict__ fc2_w,
                                                    const float* __restrict__ fc2_b,
                                                    const float* __restrict__ sq_w,
                                                    const float* __restrict__ sq_b,
                                                    const float* __restrict__ sk_b,
                                                    unsigned short* __restrict__ Bt,
                                                    float* __restrict__ skwT,
                                                    float* __restrict__ pos,
                                                    int* __restrict__ flagp,
                                                    float* __restrict__ Wf,
                                                    float* __restrict__ bfold,
                                                    float* __restrict__ W2buf,
                                                    float* __restrict__ v2,
                                                    float* __restrict__ gbuf){
  int sub = blockIdx.x;
  int t = threadIdx.x;
  if (sub < 2048){
    long id = (long)sub * 256 + t;
    int n = (int)(id >> 9), k = (int)(id & 511);
    Bt[id] = (unsigned short)f2bf(kvw[(long)k * NKV + n]);
  } else if (sub < 3072){
    long id = (long)(sub - 2048) * 256 + t;
    int e = (int)(id >> 9), j = (int)(id & 511);
    skwT[(long)j * 512 + e] = skw[id];
  } else if (sub < 3136){
    int s = sub - 3072;            // 0..63
    int c = s >> 1;                // 0..31
    int d = (s & 1) * 256 + t;     // 0..511
    int j = (d < 256) ? d : d - 256;
    float invf = expf(-((2.0f * (float)j) / 512.0f) * 9.2103403719761836f);
    float arg = (float)(31 - c) * invf;
    pos[c * 512 + d] = (d < 256) ? sinf(arg) : cosf(arg);
    if (s == 0 && t == 0){
      const unsigned char* mb = (const unsigned char*)mask;
      *flagp = (mb[1] != 0) ? 1 : 0;
    }
  } else if (sub < 3146){
    int s = sub - 3136;            // 0..9
    int j = s >> 1;                // 0..4
    int d = (s & 1) * 256 + t;
    float acc = 0.f;
    for (int k = 0; k < 512; ++k) acc += out_w[(long)d * 512 + k] * fc2_w[k * 5 + j];
    Wf[d * 5 + j] = acc;
    if (d == 0){
      float sb = 0.f;
      for (int k = 0; k < 512; ++k) sb += out_b[k] * fc2_w[k * 5 + j];
      bfold[j] = sb + fc2_b[j];
    }
  } else {
    int s = sub - 3146;            // 0..4
    if (s < 2){
      int d = s * 256 + t;
      float acc = 0.f;
      for (int j = 0; j < 512; ++j) acc += sq_w[(long)d * 512 + j] * sk_b[j];
      W2buf[(long)d * W2LD + 512] = acc;
      for (int c = 513; c < W2LD; ++c) W2buf[(long)d * W2LD + c] = 0.f;
    } else if (s < 4){
      int e = (s - 2) * 256 + t;
      float acc = 0.f;
      for (int j = 0; j < 512; ++j) acc += skw[(long)e * 512 + j] * sq_b[j];
      v2[e] = acc;
    } else {
      __shared__ float g[256];
      g[t] = sq_b[t] * sk_b[t] + sq_b[t + 256] * sk_b[t + 256];
      __syncthreads();
      for (int d = 128; d >= 1; d >>= 1){
        if (t < d) g[t] += g[t + d];
        __syncthreads();
      }
      if (t == 0) gbuf[0] = g[0];
    }
  }
}

// ---------------- fused: memories -> summ + chunkden + bf16 (mem+pos), load-batched ----------------
__global__ __launch_bounds__(512) void prepsum_kernel(const float* __restrict__ memories,
                                                      const float* __restrict__ pos,
                                                      const void* __restrict__ mask,
                                                      const int* __restrict__ flagp,
                                                      unsigned short* __restrict__ abf_all,
                                                      float* __restrict__ summ,
                                                      float* __restrict__ chunkden){
  int n = blockIdx.x, b = blockIdx.y;
  int t = threadIdx.x;
  unsigned short* abf = abf_all ? abf_all + (long)b * MPAD * 512 : nullptr;
  if (n == NCHUNK){
    if (abf){
      for (int idx = t; idx < 96 * 128; idx += 512){
        ushort4 z = {0, 0, 0, 0};
        *(ushort4*)(abf + (long)(NMEM + (idx >> 7)) * 512 + (long)(idx & 127) * 4) = z;
      }
    }
    return;
  }
  long mbase = (long)b * NMEM + (long)n * CHUNK;
  int c4 = t & 127;
  int rh = t >> 7;               // 0..3
  const float* base = memories + mbase * HID;
  // batch-issue all 8 memory loads, then pos loads, then convert/store/accumulate
  float4 v[8], p4[8];
#pragma unroll
  for (int j = 0; j < 8; ++j)
    v[j] = *(const float4*)(base + (long)(rh + 4 * j) * HID + c4 * 4);
#pragma unroll
  for (int j = 0; j < 8; ++j)
    p4[j] = *(const float4*)(pos + (rh + 4 * j) * HID + c4 * 4);
  int flag = *flagp;
  unsigned int m32 = 0;
  for (int c = 0; c < 32; ++c) m32 |= (mask_at(mask, flag, mbase + c) ? 1u : 0u) << c;
  float den = (float)__popc(m32);
  if (abf){
#pragma unroll
    for (int j = 0; j < 8; ++j){
      ushort4 o;
      o.x = (unsigned short)f2bf(v[j].x + p4[j].x);
      o.y = (unsigned short)f2bf(v[j].y + p4[j].y);
      o.z = (unsigned short)f2bf(v[j].z + p4[j].z);
      o.w = (unsigned short)f2bf(v[j].w + p4[j].w);
      *(ushort4*)(abf + (long)(n * CHUNK + rh + 4 * j) * 512 + c4 * 4) = o;
    }
  }
  float4 acc = {0.f, 0.f, 0.f, 0.f};
#pragma unroll
  for (int j = 0; j < 8; ++j){
    if (m32 & (1u << (rh + 4 * j))){
      acc.x += v[j].x; acc.y += v[j].y; acc.z += v[j].z; acc.w += v[j].w;
    }
  }
  __shared__ float4 red[512];
  red[t] = acc;
  __syncthreads();
  if (rh == 0){
    float4 a0 = red[t], a1 = red[t + 128], a2 = red[t + 256], a3 = red[t + 384];
    float dv = den + 1e-5f;
    float4 s4;
    s4.x = (a0.x + a1.x + a2.x + a3.x) / dv;
    s4.y = (a0.y + a1.y + a2.y + a3.y) / dv;
    s4.z = (a0.z + a1.z + a2.z + a3.z) / dv;
    s4.w = (a0.w + a1.w + a2.w + a3.w) / dv;
    *(float4*)(summ + ((long)b * NCHUNK + n) * 512 + c4 * 4) = s4;
    if (t == 0) chunkden[b * NCHUNK + n] = den;
  }
}

// ---------------- prep (fallback): (mem+pos) -> bf16 A[MPAD][512] ----------------
__global__ __launch_bounds__(256) void prep_kernel(const float* __restrict__ mem,
                                                   const float* __restrict__ pos,
                                                   unsigned short* __restrict__ Abf){
  long idx = (long)blockIdx.x * 256 + threadIdx.x;
  int r = (int)(idx >> 7);
  int cv = (int)(idx & 127) << 2;
  ushort4 o;
  if (r < NMEM){
    float4 m4 = *(const float4*)(mem + (long)r * 512 + cv);
    float4 p4 = *(const float4*)(pos + (r & 31) * 512 + cv);
    o.x = (unsigned short)f2bf(m4.x + p4.x);
    o.y = (unsigned short)f2bf(m4.y + p4.y);
    o.z = (unsigned short)f2bf(m4.z + p4.z);
    o.w = (unsigned short)f2bf(m4.w + p4.w);
  } else {
    o.x = o.y = o.z = o.w = 0;
  }
  *(ushort4*)(Abf + idx * 4) = o;
}

// ---------------- generic f32 NN GEMM: C = A[M][K] @ B[K][N] * scale ----------------
__global__ __launch_bounds__(256) void gemm_nn(const float* __restrict__ A, int lda,
                                               const float* __restrict__ B, int ldb,
                                               float* __restrict__ C, int ldc,
                                               int K, float scale){
  int tid = threadIdx.x;
  int lane = tid & 63, w = tid >> 6;
  int r0 = blockIdx.x * 16 + w * 4;
  int n  = blockIdx.y * 64 + lane;
  const float* a0 = A + (long)r0 * lda;
  const float* bp = B + n;
  float acc0 = 0.f, acc1 = 0.f, acc2 = 0.f, acc3 = 0.f;
#pragma unroll 2
  for (int k = 0; k < K; k += 4){
    float b0 = bp[(long)k * ldb];
    float b1 = bp[(long)(k + 1) * ldb];
    float b2 = bp[(long)(k + 2) * ldb];
    float b3 = bp[(long)(k + 3) * ldb];
    float4 a;
    a = *(const float4*)(a0 + k);
    acc0 += a.x * b0 + a.y * b1 + a.z * b2 + a.w * b3;
    a = *(const float4*)(a0 + lda + k);
    acc1 += a.x * b0 + a.y * b1 + a.z * b2 + a.w * b3;
    a = *(const float4*)(a0 + 2 * lda + k);
    acc2 += a.x * b0 + a.y * b1 + a.z * b2 + a.w * b3;
    a = *(const float4*)(a0 + 3 * lda + k);
    acc3 += a.x * b0 + a.y * b1 + a.z * b2 + a.w * b3;
  }
  C[(long)r0 * ldc + n]       = acc0 * scale;
  C[(long)(r0 + 1) * ldc + n] = acc1 * scale;
  C[(long)(r0 + 2) * ldc + n] = acc2 * scale;
  C[(long)(r0 + 3) * ldc + n] = acc3 * scale;
}

// ---------------- uq: u_ext = queries@W2buf (y<9) and qh = queries@q_w*0.125 (y>=9) ----------------
// 2 rows per wave: grid (64, 17)
__global__ __launch_bounds__(256) void uq_kernel(const float* __restrict__ queries,
                                                 const float* __restrict__ W2buf,
                                                 const float* __restrict__ q_w,
                                                 float* __restrict__ u_ext,
                                                 float* __restrict__ qh){
  int y = blockIdx.y;
  const float* B; int ldb; float* C; int ldc; int nbase; float scale;
  if (y < 9){ B = W2buf; ldb = W2LD; C = u_ext; ldc = W2LD; nbase = y * 64; scale = 1.0f; }
  else      { B = q_w;   ldb = 512;  C = qh;    ldc = 512;  nbase = (y - 9) * 64; scale = 0.125f; }
  int tid = threadIdx.x;
  int lane = tid & 63, w = tid >> 6;
  int r0 = blockIdx.x * 8 + w * 2;
  int n  = nbase + lane;
  const float* a0 = queries + (long)r0 * 512;
  const float* bp = B + n;
  float acc0 = 0.f, acc1 = 0.f;
#pragma unroll 4
  for (int k = 0; k < 512; k += 4){
    float b0 = bp[(long)k * ldb];
    float b1 = bp[(long)(k + 1) * ldb];
    float b2 = bp[(long)(k + 2) * ldb];
    float b3 = bp[(long)(k + 3) * ldb];
    float4 a;
    a = *(const float4*)(a0 + k);
    acc0 += a.x * b0 + a.y * b1 + a.z * b2 + a.w * b3;
    a = *(const float4*)(a0 + 512 + k);
    acc1 += a.x * b0 + a.y * b1 + a.z * b2 + a.w * b3;
  }
  C[(long)r0 * ldc + n]       = acc0 * scale;
  C[(long)(r0 + 1) * ldc + n] = acc1 * scale;
}

// ---------------- stbeta: summText build (blocks <5200) + betag (blocks >=5200) ----------------
__global__ __launch_bounds__(256) void stbeta_kernel(const float* __restrict__ summ,
                                                     const float* __restrict__ v2,
                                                     const float* __restrict__ gbuf,
                                                     float* __restrict__ summText,
                                                     float* __restrict__ betag){
  if (blockIdx.x < 5200){
    long id = (long)blockIdx.x * 256 + threadIdx.x;   // 4*520*640 = 1,331,200
    int b = (int)(id / (STROWS * LGLD));
    int rem = (int)(id - (long)b * STROWS * LGLD);
    int e = rem / LGLD, n = rem % LGLD;
    float v;
    if (e < 512)       v = (n < NCHUNK) ? summ[((long)b * NCHUNK + n) * 512 + e] : 0.f;
    else if (e == 512) v = 1.f;
    else               v = 0.f;
    summText[id] = v;
  } else {
    int blk = blockIdx.x - 5200;           // 0..624
    int w = threadIdx.x >> 6, lane = threadIdx.x & 63;
    int row = blk * 4 + w;                 // 0..2499
    const float* r = summ + (long)row * 512;
    float s = 0.f;
#pragma unroll
    for (int c = 0; c < 8; ++c) s += r[lane + 64 * c] * v2[lane + 64 * c];
    for (int d = 32; d >= 1; d >>= 1) s += __shfl_xor(s, d, 64);
    if (lane == 0){
      int b = row / NCHUNK, n = row % NCHUNK;
      betag[b * LGLD + n] = s + gbuf[0];
    }
  }
}

// ---------------- logits (NN form): 2 rows/wave, grid (16,10,NB) ----------------
__global__ __launch_bounds__(256) void logits_nn(const float* __restrict__ u_ext,
                                                 const float* __restrict__ summText,
                                                 const float* __restrict__ betag,
                                                 const float* __restrict__ chunkden,
                                                 float* __restrict__ logits){
  int b = blockIdx.z;
  int tid = threadIdx.x;
  int lane = tid & 63, w = tid >> 6;
  int r0 = blockIdx.x * 8 + w * 2;       // i
  int n  = blockIdx.y * 64 + lane;
  const float* a0 = u_ext + ((long)b * QN + r0) * W2LD;
  const float* bp = summText + (long)b * STROWS * LGLD + n;
  float acc0 = 0.f, acc1 = 0.f;
#pragma unroll 4
  for (int k = 0; k < STROWS; k += 4){
    float b0 = bp[(long)k * LGLD];
    float b1 = bp[(long)(k + 1) * LGLD];
    float b2 = bp[(long)(k + 2) * LGLD];
    float b3 = bp[(long)(k + 3) * LGLD];
    float4 a;
    a = *(const float4*)(a0 + k);
    acc0 += a.x * b0 + a.y * b1 + a.z * b2 + a.w * b3;
    a = *(const float4*)(a0 + W2LD + k);
    acc1 += a.x * b0 + a.y * b1 + a.z * b2 + a.w * b3;
  }
  if (n < NCHUNK){
    float bet = betag[b * LGLD + n];
    bool dead = (chunkden[b * NCHUNK + n] <= 0.f);
    float v0 = (acc0 + bet) * LOGIT_SCALE;
    float v1 = (acc1 + bet) * LOGIT_SCALE;
    if (dead){ v0 = v1 = -FLT_MAX; }
    long base = ((long)b * QN + r0) * LGLD + n;
    logits[base]        = v0;
    logits[base + LGLD] = v1;
  }
}

// ---------------- top-8 + softmax weights, 4 waves per (b,i) row ----------------
__global__ __launch_bounds__(256) void topk_kernel(const float* __restrict__ logits,
                                                   int* __restrict__ topi_out,
                                                   float* __restrict__ wts_out){
  int row = blockIdx.x;   // b*128+i
  __shared__ float lds[NCHUNK];
  __shared__ float wv[4];
  __shared__ int   wi[4];
  __shared__ float topv[TOPKK];
  __shared__ int   topi[TOPKK];
  int t = threadIdx.x;
  int lane = t & 63, w = t >> 6;
  for (int idx = t; idx < NCHUNK; idx += 256) lds[idx] = logits[(long)row * LGLD + idx];
  __syncthreads();
  for (int it = 0; it < TOPKK; ++it){
    float bv = -INFINITY; int bi = 0x7fffffff;
    for (int idx = t; idx < NCHUNK; idx += 256){
      float v = lds[idx];
      if (v > bv){ bv = v; bi = idx; }    // ascending idx => lowest index kept on ties
    }
    for (int d = 32; d >= 1; d >>= 1){
      float ov = __shfl_xor(bv, d, 64);
      int   oi = __shfl_xor(bi, d, 64);
      if (ov > bv || (ov == bv && oi < bi)){ bv = ov; bi = oi; }
    }
    if (lane == 0){ wv[w] = bv; wi[w] = bi; }
    __syncthreads();
    if (t == 0){
      float fb = wv[0]; int fi = wi[0];
      for (int j = 1; j < 4; ++j){
        if (wv[j] > fb || (wv[j] == fb && wi[j] < fi)){ fb = wv[j]; fi = wi[j]; }
      }
      topv[it] = fb; topi[it] = fi; lds[fi] = -INFINITY;
    }
    __syncthreads();
  }
  if (t == 0){
    float m = topv[0];
    for (int r = 1; r < TOPKK; ++r) m = fmaxf(m, topv[r]);
    float e[TOPKK], s = 0.f;
    for (int r = 0; r < TOPKK; ++r){ e[r] = expf(topv[r] - m); s += e[r]; }
    for (int r = 0; r < TOPKK; ++r){
      wts_out[(long)row * TOPKK + r] = e[r] / s;
      topi_out[(long)row * TOPKK + r] = topi[r];
    }
  }
}

// ---------------- KV GEMM, dbuf, XCD-aware remap, multi-batch ----------------
__global__ __launch_bounds__(256) void kv_gemm(const unsigned short* __restrict__ A_all,
                                               const unsigned short* __restrict__ Bt,
                                               unsigned short* __restrict__ kv_all,
                                               int npanels){
  int L = blockIdx.x;
  int panel = ((L >> 6) << 3) | (L & 7);
  int nb = (L >> 3) & 7;
  if (panel >= npanels) return;
  int bb = panel / 157;
  int p  = panel - bb * 157;
  const unsigned short* A = A_all + (size_t)bb * MPAD * 512;
  unsigned short* kvout   = kv_all + (size_t)bb * MPAD * NKV;

  __shared__ unsigned short As[2][128 * 32];
  __shared__ unsigned short Bs[2][128 * 32];
  int m0 = p << 7, n0 = nb << 7;
  int tid = threadIdx.x;
  int wid = tid >> 6, lane = tid & 63;
  int wr = wid >> 1, wc = wid & 1;
  int lr = lane & 15, lg = lane >> 4;

  int srow = wid * 16 + (lane >> 2);
  int scol = (lane & 3) << 3;
  const unsigned short* gA0 = A  + (long)(m0 + srow) * 512 + scol;
  const unsigned short* gA1 = gA0 + 64 * 512;
  const unsigned short* gB0 = Bt + (long)(n0 + srow) * 512 + scol;
  const unsigned short* gB1 = gB0 + 64 * 512;
  int lofs0 = (wid * 16) * 32;
  int lofs1 = (64 + wid * 16) * 32;

  f32x4 acc[4][4];
#pragma unroll
  for (int i = 0; i < 4; ++i)
#pragma unroll
    for (int j = 0; j < 4; ++j) acc[i][j] = (f32x4)0.f;

#define STAGE(B, K0) { gload16(gA0 + (K0), &As[B][lofs0]); gload16(gA1 + (K0), &As[B][lofs1]); \
                       gload16(gB0 + (K0), &Bs[B][lofs0]); gload16(gB1 + (K0), &Bs[B][lofs1]); }
#define COMPUTE(B) { bf16x8 af[4], bfv[4]; \
  _Pragma("unroll") for (int mi = 0; mi < 4; ++mi) af[mi]  = *(const bf16x8*)&As[B][(wr * 64 + mi * 16 + lr) * 32 + lg * 8]; \
  _Pragma("unroll") for (int ni = 0; ni < 4; ++ni) bfv[ni] = *(const bf16x8*)&Bs[B][(wc * 64 + ni * 16 + lr) * 32 + lg * 8]; \
  _Pragma("unroll") for (int mi = 0; mi < 4; ++mi) \
    _Pragma("unroll") for (int ni = 0; ni < 4; ++ni) \
      acc[mi][ni] = __builtin_amdgcn_mfma_f32_16x16x32_bf16(af[mi], bfv[ni], acc[mi][ni], 0, 0, 0); }

  STAGE(0, 0);
  __syncthreads();
#pragma unroll 1
  for (int t = 0; t < 16; t += 2){
    if (t + 1 < 16) STAGE(1, (t + 1) * 32);
    COMPUTE(0);
    __syncthreads();
    if (t + 2 < 16) STAGE(0, (t + 2) * 32);
    COMPUTE(1);
    __syncthreads();
  }
#undef STAGE
#undef COMPUTE

#pragma unroll
  for (int mi = 0; mi < 4; ++mi)
#pragma unroll
    for (int ni = 0; ni < 4; ++ni)
#pragma unroll
      for (int rr = 0; rr < 4; ++rr){
        int gr = m0 + wr * 64 + mi * 16 + lg * 4 + rr;
        int gn = n0 + wc * 64 + ni * 16 + lr;
        kvout[(long)gr * NKV + gn] = (unsigned short)f2bf(acc[mi][ni][rr]);
      }
}

// ---------------- attention; bb_arg<0 => batched (grid 4096, per-batch kv stride) ----------------
__global__ __launch_bounds__(256) void attn_kernel(const float* __restrict__ qh,
                                                   const unsigned short* __restrict__ kv,
                                                   const int* __restrict__ topidx,
                                                   const float* __restrict__ wts,
                                                   const void* __restrict__ mask,
                                                   const int* __restrict__ flagp,
                                                   float* __restrict__ osc,
                                                   int bb_arg){
  int bx = blockIdx.x;
  int bb, rem;
  const unsigned short* kvb;
  if (bb_arg < 0){
    bb = bx >> 10; rem = bx & 1023;
    kvb = kv + (size_t)bb * MPAD * NKV;
  } else {
    bb = bb_arg; rem = bx;
    kvb = kv;
  }
  int i = rem >> 3, k = rem & 7;
  int t = threadIdx.x;
  __shared__ float qs[HID];
  __shared__ float att[HEADS][CHUNK + 1];
  long sel = ((long)(bb * QN + i)) * TOPKK + k;
  int chunk = topidx[sel];
  float w8 = wts[sel];
  const float* qrow = qh + ((long)(bb * QN + i)) * HID;
  qs[t] = qrow[t]; qs[t + 256] = qrow[t + 256];
  __syncthreads();
  int flag = *flagp;
  int h = t >> 5, c = t & 31;
  const unsigned short* krow = kvb + ((long)(chunk * CHUNK + c)) * NKV + h * DHEAD;
  float s = 0.f;
#pragma unroll
  for (int e8 = 0; e8 < 8; ++e8){
    bf16x8 k8 = *(const bf16x8*)(krow + e8 * 8);
#pragma unroll
    for (int j = 0; j < 8; ++j) s += qs[h * DHEAD + e8 * 8 + j] * bf2f((unsigned short)k8[j]);
  }
  bool mv = mask_at(mask, flag, (long)bb * NMEM + (long)chunk * CHUNK + c);
  if (!mv) s = -FLT_MAX;
  float m = s;
  for (int d = 16; d >= 1; d >>= 1) m = fmaxf(m, __shfl_xor(m, d, 32));
  float p = expf(s - m);
  float su = p;
  for (int d = 16; d >= 1; d >>= 1) su += __shfl_xor(su, d, 32);
  att[h][c] = p / su;
  __syncthreads();
  int e0 = (t & 31) * 2;
  float o0 = 0.f, o1 = 0.f;
#pragma unroll 8
  for (int c2 = 0; c2 < CHUNK; ++c2){
    float a = att[h][c2];
    unsigned int pv = *(const unsigned int*)(kvb + ((long)(chunk * CHUNK + c2)) * NKV + 512 + h * DHEAD + e0);
    o0 += a * bf2f((unsigned short)(pv & 0xffff));
    o1 += a * bf2f((unsigned short)(pv >> 16));
  }
  long ob = (((long)(bb * QN + i) * TOPKK) + k) * HID + h * DHEAD + e0;
  osc[ob]     = o0 * w8;
  osc[ob + 1] = o1 * w8;
}

// ---------------- final: reduce over k, then @ (out_w@fc2_w) + folded bias ----------------
__global__ __launch_bounds__(512) void final_kernel(const float* __restrict__ osc,
                                                    const float* __restrict__ Wf,
                                                    const float* __restrict__ bfold,
                                                    float* __restrict__ out){
  int bi = blockIdx.x;   // b*128+i
  int t = threadIdx.x;
  __shared__ float lds[HID];
  float s = 0.f;
  for (int k = 0; k < TOPKK; ++k) s += osc[(((long)bi * TOPKK) + k) * HID + t];
  lds[t] = s;
  __syncthreads();
  int w = t >> 6, lane = t & 63;
  if (w < 5){
    float a = 0.f;
#pragma unroll
    for (int c = 0; c < 8; ++c) a += lds[lane + 64 * c] * Wf[(lane + 64 * c) * 5 + w];
    for (int d = 32; d >= 1; d >>= 1) a += __shfl_xor(a, d, 64);
    if (lane == 0) out[bi * 5 + w] = a + bfold[w];
  }
}

extern "C" void kernel_launch(void* const* d_in, const int* in_sizes, int n_in,
                              void* d_out, int out_size, void* d_ws, size_t ws_size,
                              hipStream_t stream) {
  const float* queries  = (const float*)d_in[1];
  const float* memories = (const float*)d_in[2];
  const void*  mask     = d_in[3];
  const float* sq_w = (const float*)d_in[10];
  const float* sq_b = (const float*)d_in[11];
  const float* sk_w = (const float*)d_in[12];
  const float* sk_b = (const float*)d_in[13];
  const float* q_w  = (const float*)d_in[14];
  const float* kv_w = (const float*)d_in[15];
  const float* out_w = (const float*)d_in[16];
  const float* out_b = (const float*)d_in[17];
  const float* fc2_w = (const float*)d_in[18];
  const float* fc2_b = (const float*)d_in[19];
  float* out = (float*)d_out;

  char* ws = (char*)d_ws;
  size_t o_sum  = 0;                        // 5,120,000
  size_t o_den  = o_sum + 5120000;          // 10,240
  size_t o_pos  = o_den + 10240;            // 65,536
  size_t o_wf   = o_pos + 65536;            // 10,240
  size_t o_bf   = o_wf  + 10240;            // 512
  size_t o_ti   = o_bf  + 512;              // 16,384
  size_t o_wt   = o_ti  + 16384;            // 16,384
  size_t o_flag = o_wt  + 16384;            // 512
  size_t o_qh   = o_flag + 512;             // 1,048,576
  size_t o_w2   = o_qh  + 1048576;          // 1,179,648
  size_t o_uex  = o_w2  + 1179648;          // 1,179,648
  size_t o_st   = o_uex + 1179648;          // 5,324,800
  size_t o_bg   = o_st  + 5324800;          // 10,240
  size_t o_v2   = o_bg  + 10240;            // 2,048
  size_t o_gm   = o_v2  + 2048;             // 512
  size_t o_lg   = o_gm  + 512;              // 1,310,720
  size_t o_osc  = o_lg  + 1310720;          // 8,388,608
  size_t o_skt  = o_osc + 8388608;          // 1,048,576
  size_t o_abf  = o_skt + 1048576;

  const size_t ABF_ONE = (size_t)MPAD * 512 * 2;          // 20,578,304
  const size_t ABF_ALL = ABF_ONE * NB;                    // 82,313,216
  const size_t KV_ONE  = (size_t)MPAD * NKV * 2;          // 41,156,608
  size_t need_fused   = o_abf + ABF_ALL + 1048576 + KV_ONE;
  size_t need_batched = o_abf + ABF_ALL + 1048576 + KV_ONE * NB;
  bool fused   = (ws_size >= need_fused);
  bool batched = (ws_size >= need_batched);
  size_t abf_bytes = fused ? ABF_ALL : ABF_ONE;
  size_t o_btw = o_abf + abf_bytes;
  size_t o_kv  = o_btw + 1048576;

  float* summ  = (float*)(ws + o_sum);
  float* den   = (float*)(ws + o_den);
  float* pos   = (float*)(ws + o_pos);
  float* Wf    = (float*)(ws + o_wf);
  float* bfold = (float*)(ws + o_bf);
  int*   ti    = (int*)  (ws + o_ti);
  float* wt    = (float*)(ws + o_wt);
  int*   flagp = (int*)  (ws + o_flag);
  float* qh    = (float*)(ws + o_qh);
  float* W2buf = (float*)(ws + o_w2);
  float* u_ext = (float*)(ws + o_uex);
  float* summText = (float*)(ws + o_st);
  float* betag = (float*)(ws + o_bg);
  float* v2    = (float*)(ws + o_v2);
  float* gbuf  = (float*)(ws + o_gm);
  float* logit = (float*)(ws + o_lg);
  float* osc   = (float*)(ws + o_osc);
  float* skwT  = (float*)(ws + o_skt);
  unsigned short* abf   = (unsigned short*)(ws + o_abf);
  unsigned short* btw   = (unsigned short*)(ws + o_btw);
  unsigned short* kvbuf = (unsigned short*)(ws + o_kv);

  setup_kernel<<<dim3(3151), dim3(256), 0, stream>>>(
      kv_w, sk_w, mask, out_w, out_b, fc2_w, fc2_b, sq_w, sq_b, sk_b,
      btw, skwT, pos, flagp, Wf, bfold, W2buf, v2, gbuf);

  prepsum_kernel<<<dim3(NCHUNK + 1, NB), dim3(512), 0, stream>>>(
      memories, pos, mask, flagp, fused ? abf : nullptr, summ, den);

  // selection path (f32-exact)
  gemm_nn<<<dim3(32, 8), dim3(256), 0, stream>>>(sq_w, 512, skwT, 512, W2buf, W2LD, 512, 1.0f);
  uq_kernel<<<dim3(64, 17), dim3(256), 0, stream>>>(queries, W2buf, q_w, u_ext, qh);
  stbeta_kernel<<<dim3(5200 + 625), dim3(256), 0, stream>>>(summ, v2, gbuf, summText, betag);
  logits_nn<<<dim3(16, 10, NB), dim3(256), 0, stream>>>(u_ext, summText, betag, den, logit);
  topk_kernel<<<dim3(NB * QN), dim3(256), 0, stream>>>(logit, ti, wt);

  if (batched){
    kv_gemm<<<dim3(((NB * 157 + 7) / 8) * 64), dim3(256), 0, stream>>>(abf, btw, kvbuf, NB * 157);
    attn_kernel<<<dim3(NB * QN * TOPKK), dim3(256), 0, stream>>>(qh, kvbuf, ti, wt, mask, flagp, osc, -1);
  } else {
    for (int bb = 0; bb < NB; ++bb){
      const unsigned short* Ab;
      if (fused){
        Ab = abf + (size_t)bb * MPAD * 512;
      } else {
        prep_kernel<<<dim3(10048), dim3(256), 0, stream>>>(memories + (long)bb * NMEM * HID, pos, abf);
        Ab = abf;
      }
      kv_gemm<<<dim3(((157 + 7) / 8) * 64), dim3(256), 0, stream>>>(Ab, btw, kvbuf, 157);
      attn_kernel<<<dim3(QN * TOPKK), dim3(256), 0, stream>>>(qh, kvbuf, ti, wt, mask, flagp, osc, bb);
    }
  }
  final_kernel<<<dim3(NB * QN), dim3(512), 0, stream>>>(osc, Wf, bfold, out);
}

// Round 7
// 422.239 us; speedup vs baseline: 1.5141x; 1.0031x over previous
//
#include <hip/hip_runtime.h>
#include <hip/hip_bf16.h>
#include <float.h>
#include <math.h>

// Problem constants
#define NB      4
#define QN      128
#define HID     512
#define NMEM    20000
#define MPAD    20096    // 157*128
#define NCHUNK  625
#define CHUNK   32
#define HEADS   8
#define DHEAD   64
#define TOPKK   8
#define NKV     1024   // 2*HEADS*DHEAD
#define LOGIT_SCALE 0.044194173824159216f  // 512^-0.5
#define W2LD    576    // W2buf / u_ext leading dim (512 + 1 alpha col + pad)
#define STROWS  520    // summText rows: 512 + ones row + 7 zero rows
#define LGLD    640    // logits leading dim

typedef __attribute__((ext_vector_type(8))) short bf16x8;
typedef __attribute__((ext_vector_type(4))) float f32x4;

__device__ __forceinline__ short f2bf(float f){
  __hip_bfloat16 h = __float2bfloat16(f);
  return *reinterpret_cast<short*>(&h);
}
__device__ __forceinline__ float bf2f(unsigned short s){
  __hip_bfloat16 h;
  *reinterpret_cast<unsigned short*>(&h) = s;
  return __bfloat162float(h);
}
__device__ __forceinline__ bool mask_at(const void* m, int flag, long i){
  return flag ? (((const unsigned char*)m)[i] != 0)
              : (((const int*)m)[i] != 0);
}
__device__ __forceinline__ void gload16(const void* g, void* l){
  __builtin_amdgcn_global_load_lds((const __attribute__((address_space(1))) void*)g,
                                   (__attribute__((address_space(3))) void*)l, 16, 0, 0);
}

// ---------------- setup: tiled transposes + misc + fold + vker, one launch ----------------
// grid 271 x 256:
//   [0,128)    wtr tiles:  Bt[n][k] bf16 = kv_w[k][n]   (64k x 64n LDS tiles)
//   [128,192)  skwt tiles: skwT[j][e] = sk_w[e][j]      (64x64 LDS tiles)
//   [192,256)  misc: pos table + mask flag
//   [256,266)  fold: Wf = out_w @ fc2_w (+ folded bias)
//   [266,271)  vker: v1 -> W2buf col512 (+pad), v2, gamma
__global__ __launch_bounds__(256) void setup_kernel(const float* __restrict__ kvw,
                                                    const float* __restrict__ skw,
                                                    const void* __restrict__ mask,
                                                    const float* __restrict__ out_w,
                                                    const float* __restrict__ out_b,
                                                    const float* __restrict__ fc2_w,
                                                    const float* __restrict__ fc2_b,
                                                    const float* __restrict__ sq_w,
                                                    const float* __restrict__ sq_b,
                                                    const float* __restrict__ sk_b,
                                                    unsigned short* __restrict__ Bt,
                                                    float* __restrict__ skwT,
                                                    float* __restrict__ pos,
                                                    int* __restrict__ flagp,
                                                    float* __restrict__ Wf,
                                                    float* __restrict__ bfold,
                                                    float* __restrict__ W2buf,
                                                    float* __restrict__ v2,
                                                    float* __restrict__ gbuf){
  __shared__ float tile[64][65];
  int sub = blockIdx.x;
  int t = threadIdx.x;
  int c = t & 63, rbase = t >> 6;
  if (sub < 128){
    int k0 = (sub >> 4) * 64, n0 = (sub & 15) * 64;
#pragma unroll
    for (int j = 0; j < 16; ++j){
      int r = rbase + j * 4;
      tile[r][c] = kvw[(long)(k0 + r) * NKV + n0 + c];
    }
    __syncthreads();
#pragma unroll
    for (int j = 0; j < 16; ++j){
      int rn = rbase + j * 4;
      Bt[(long)(n0 + rn) * 512 + k0 + c] = (unsigned short)f2bf(tile[c][rn]);
    }
  } else if (sub < 192){
    int s = sub - 128;
    int e0 = (s >> 3) * 64, j0 = (s & 7) * 64;
#pragma unroll
    for (int j = 0; j < 16; ++j){
      int r = rbase + j * 4;
      tile[r][c] = skw[(long)(e0 + r) * 512 + j0 + c];
    }
    __syncthreads();
#pragma unroll
    for (int j = 0; j < 16; ++j){
      int rj = rbase + j * 4;
      skwT[(long)(j0 + rj) * 512 + e0 + c] = tile[c][rj];
    }
  } else if (sub < 256){
    int s = sub - 192;             // 0..63
    int cc = s >> 1;               // 0..31
    int d = (s & 1) * 256 + t;     // 0..511
    int j = (d < 256) ? d : d - 256;
    float invf = expf(-((2.0f * (float)j) / 512.0f) * 9.2103403719761836f);
    float arg = (float)(31 - cc) * invf;
    pos[cc * 512 + d] = (d < 256) ? sinf(arg) : cosf(arg);
    if (s == 0 && t == 0){
      const unsigned char* mb = (const unsigned char*)mask;
      *flagp = (mb[1] != 0) ? 1 : 0;
    }
  } else if (sub < 266){
    int s = sub - 256;             // 0..9
    int j = s >> 1;                // 0..4
    int d = (s & 1) * 256 + t;
    const float4* owr = (const float4*)(out_w + (long)d * 512);
    float acc = 0.f;
    for (int k4 = 0; k4 < 128; ++k4){
      float4 a = owr[k4];
      int k = k4 * 4;
      acc += a.x * fc2_w[k * 5 + j] + a.y * fc2_w[(k + 1) * 5 + j]
           + a.z * fc2_w[(k + 2) * 5 + j] + a.w * fc2_w[(k + 3) * 5 + j];
    }
    Wf[d * 5 + j] = acc;
    if (d == 0){
      float sb = 0.f;
      for (int k = 0; k < 512; ++k) sb += out_b[k] * fc2_w[k * 5 + j];
      bfold[j] = sb + fc2_b[j];
    }
  } else {
    int s = sub - 266;             // 0..4
    if (s < 2){
      int d = s * 256 + t;
      float acc = 0.f;
      for (int j = 0; j < 512; ++j) acc += sq_w[(long)d * 512 + j] * sk_b[j];
      W2buf[(long)d * W2LD + 512] = acc;
      for (int cc = 513; cc < W2LD; ++cc) W2buf[(long)d * W2LD + cc] = 0.f;
    } else if (s < 4){
      int e = (s - 2) * 256 + t;
      float acc = 0.f;
      for (int j = 0; j < 512; ++j) acc += skw[(long)e * 512 + j] * sq_b[j];
      v2[e] = acc;
    } else {
      __shared__ float g[256];
      g[t] = sq_b[t] * sk_b[t] + sq_b[t + 256] * sk_b[t + 256];
      __syncthreads();
      for (int d = 128; d >= 1; d >>= 1){
        if (t < d) g[t] += g[t + d];
        __syncthreads();
      }
      if (t == 0) gbuf[0] = g[0];
    }
  }
}

// ---------------- fused: memories -> summ + chunkden + bf16 (mem+pos) ----------------
__global__ __launch_bounds__(512) void prepsum_kernel(const float* __restrict__ memories,
                                                      const float* __restrict__ pos,
                                                      const void* __restrict__ mask,
                                                      const int* __restrict__ flagp,
                                                      unsigned short* __restrict__ abf_all,
                                                      float* __restrict__ summ,
                                                      float* __restrict__ chunkden){
  int n = blockIdx.x, b = blockIdx.y;
  int t = threadIdx.x;
  unsigned short* abf = abf_all ? abf_all + (long)b * MPAD * 512 : nullptr;
  if (n == NCHUNK){
    if (abf){
      for (int idx = t; idx < 96 * 128; idx += 512){
        ushort4 z = {0, 0, 0, 0};
        *(ushort4*)(abf + (long)(NMEM + (idx >> 7)) * 512 + (long)(idx & 127) * 4) = z;
      }
    }
    return;
  }
  long mbase = (long)b * NMEM + (long)n * CHUNK;
  int flag = *flagp;
  // one coalesced mask load per lane + ballot -> 32-bit chunk mask (bits 0..31)
  bool mybit = mask_at(mask, flag, mbase + (t & 31));
  unsigned long long bal = __ballot(mybit);
  unsigned int m32 = (unsigned int)bal;
  float den = (float)__popc(m32);
  int c4 = t & 127;
  int rh = t >> 7;               // 0..3
  const float* base = memories + mbase * HID;
  float4 v[8], p4[8];
#pragma unroll
  for (int j = 0; j < 8; ++j)
    v[j] = *(const float4*)(base + (long)(rh + 4 * j) * HID + c4 * 4);
#pragma unroll
  for (int j = 0; j < 8; ++j)
    p4[j] = *(const float4*)(pos + (rh + 4 * j) * HID + c4 * 4);
  if (abf){
#pragma unroll
    for (int j = 0; j < 8; ++j){
      ushort4 o;
      o.x = (unsigned short)f2bf(v[j].x + p4[j].x);
      o.y = (unsigned short)f2bf(v[j].y + p4[j].y);
      o.z = (unsigned short)f2bf(v[j].z + p4[j].z);
      o.w = (unsigned short)f2bf(v[j].w + p4[j].w);
      *(ushort4*)(abf + (long)(n * CHUNK + rh + 4 * j) * 512 + c4 * 4) = o;
    }
  }
  float4 acc = {0.f, 0.f, 0.f, 0.f};
#pragma unroll
  for (int j = 0; j < 8; ++j){
    if (m32 & (1u << (rh + 4 * j))){
      acc.x += v[j].x; acc.y += v[j].y; acc.z += v[j].z; acc.w += v[j].w;
    }
  }
  __shared__ float4 red[512];
  red[t] = acc;
  __syncthreads();
  if (rh == 0){
    float4 a0 = red[t], a1 = red[t + 128], a2 = red[t + 256], a3 = red[t + 384];
    float dv = den + 1e-5f;
    float4 s4;
    s4.x = (a0.x + a1.x + a2.x + a3.x) / dv;
    s4.y = (a0.y + a1.y + a2.y + a3.y) / dv;
    s4.z = (a0.z + a1.z + a2.z + a3.z) / dv;
    s4.w = (a0.w + a1.w + a2.w + a3.w) / dv;
    *(float4*)(summ + ((long)b * NCHUNK + n) * 512 + c4 * 4) = s4;
    if (t == 0) chunkden[b * NCHUNK + n] = den;
  }
}

// ---------------- prep (fallback): (mem+pos) -> bf16 A[MPAD][512] ----------------
__global__ __launch_bounds__(256) void prep_kernel(const float* __restrict__ mem,
                                                   const float* __restrict__ pos,
                                                   unsigned short* __restrict__ Abf){
  long idx = (long)blockIdx.x * 256 + threadIdx.x;
  int r = (int)(idx >> 7);
  int cv = (int)(idx & 127) << 2;
  ushort4 o;
  if (r < NMEM){
    float4 m4 = *(const float4*)(mem + (long)r * 512 + cv);
    float4 p4 = *(const float4*)(pos + (r & 31) * 512 + cv);
    o.x = (unsigned short)f2bf(m4.x + p4.x);
    o.y = (unsigned short)f2bf(m4.y + p4.y);
    o.z = (unsigned short)f2bf(m4.z + p4.z);
    o.w = (unsigned short)f2bf(m4.w + p4.w);
  } else {
    o.x = o.y = o.z = o.w = 0;
  }
  *(ushort4*)(Abf + idx * 4) = o;
}

// ---------------- generic f32 NN GEMM: C = A[M][K] @ B[K][N] * scale ----------------
__global__ __launch_bounds__(256) void gemm_nn(const float* __restrict__ A, int lda,
                                               const float* __restrict__ B, int ldb,
                                               float* __restrict__ C, int ldc,
                                               int K, float scale){
  int tid = threadIdx.x;
  int lane = tid & 63, w = tid >> 6;
  int r0 = blockIdx.x * 16 + w * 4;
  int n  = blockIdx.y * 64 + lane;
  const float* a0 = A + (long)r0 * lda;
  const float* bp = B + n;
  float acc0 = 0.f, acc1 = 0.f, acc2 = 0.f, acc3 = 0.f;
#pragma unroll 2
  for (int k = 0; k < K; k += 4){
    float b0 = bp[(long)k * ldb];
    float b1 = bp[(long)(k + 1) * ldb];
    float b2 = bp[(long)(k + 2) * ldb];
    float b3 = bp[(long)(k + 3) * ldb];
    float4 a;
    a = *(const float4*)(a0 + k);
    acc0 += a.x * b0 + a.y * b1 + a.z * b2 + a.w * b3;
    a = *(const float4*)(a0 + lda + k);
    acc1 += a.x * b0 + a.y * b1 + a.z * b2 + a.w * b3;
    a = *(const float4*)(a0 + 2 * lda + k);
    acc2 += a.x * b0 + a.y * b1 + a.z * b2 + a.w * b3;
    a = *(const float4*)(a0 + 3 * lda + k);
    acc3 += a.x * b0 + a.y * b1 + a.z * b2 + a.w * b3;
  }
  C[(long)r0 * ldc + n]       = acc0 * scale;
  C[(long)(r0 + 1) * ldc + n] = acc1 * scale;
  C[(long)(r0 + 2) * ldc + n] = acc2 * scale;
  C[(long)(r0 + 3) * ldc + n] = acc3 * scale;
}

// ---------------- uq: u_ext = queries@W2buf (y<9) and qh = queries@q_w*0.125 (y>=9) ----------------
__global__ __launch_bounds__(256) void uq_kernel(const float* __restrict__ queries,
                                                 const float* __restrict__ W2buf,
                                                 const float* __restrict__ q_w,
                                                 float* __restrict__ u_ext,
                                                 float* __restrict__ qh){
  int y = blockIdx.y;
  const float* B; int ldb; float* C; int ldc; int nbase; float scale;
  if (y < 9){ B = W2buf; ldb = W2LD; C = u_ext; ldc = W2LD; nbase = y * 64; scale = 1.0f; }
  else      { B = q_w;   ldb = 512;  C = qh;    ldc = 512;  nbase = (y - 9) * 64; scale = 0.125f; }
  int tid = threadIdx.x;
  int lane = tid & 63, w = tid >> 6;
  int r0 = blockIdx.x * 8 + w * 2;
  int n  = nbase + lane;
  const float* a0 = queries + (long)r0 * 512;
  const float* bp = B + n;
  float acc0 = 0.f, acc1 = 0.f;
#pragma unroll 4
  for (int k = 0; k < 512; k += 4){
    float b0 = bp[(long)k * ldb];
    float b1 = bp[(long)(k + 1) * ldb];
    float b2 = bp[(long)(k + 2) * ldb];
    float b3 = bp[(long)(k + 3) * ldb];
    float4 a;
    a = *(const float4*)(a0 + k);
    acc0 += a.x * b0 + a.y * b1 + a.z * b2 + a.w * b3;
    a = *(const float4*)(a0 + 512 + k);
    acc1 += a.x * b0 + a.y * b1 + a.z * b2 + a.w * b3;
  }
  C[(long)r0 * ldc + n]       = acc0 * scale;
  C[(long)(r0 + 1) * ldc + n] = acc1 * scale;
}

// ---------------- stbeta: tiled summText transpose + extra rows + betag ----------------
// grid 949: [0,320) 64x64 transpose tiles; [320,324) per-batch rows 512..519; [324,949) beta
__global__ __launch_bounds__(256) void stbeta_kernel(const float* __restrict__ summ,
                                                     const float* __restrict__ v2,
                                                     const float* __restrict__ gbuf,
                                                     float* __restrict__ summText,
                                                     float* __restrict__ betag){
  int blk = blockIdx.x;
  int t = threadIdx.x;
  if (blk < 320){
    __shared__ float tile[64][65];
    int b = blk / 80; int rem = blk % 80;
    int n0 = (rem / 8) * 64, e0 = (rem % 8) * 64;
    int c = t & 63, rbase = t >> 6;
#pragma unroll
    for (int j = 0; j < 16; ++j){
      int r = rbase + j * 4;       // n-offset
      int n = n0 + r;
      tile[r][c] = (n < NCHUNK) ? summ[((long)b * NCHUNK + n) * 512 + e0 + c] : 0.f;
    }
    __syncthreads();
#pragma unroll
    for (int j = 0; j < 16; ++j){
      int re = rbase + j * 4;      // e-offset
      summText[(long)b * STROWS * LGLD + (long)(e0 + re) * LGLD + n0 + c] = tile[c][re];
    }
  } else if (blk < 324){
    int b = blk - 320;
    for (int idx = t; idx < 8 * LGLD; idx += 256){
      int e = idx / LGLD, n = idx - e * LGLD;
      summText[(long)b * STROWS * LGLD + (long)(512 + e) * LGLD + n] = (e == 0) ? 1.f : 0.f;
    }
  } else {
    int bb = blk - 324;            // 0..624
    int w = t >> 6, lane = t & 63;
    int row = bb * 4 + w;          // 0..2499
    const float* r = summ + (long)row * 512;
    float s = 0.f;
#pragma unroll
    for (int c = 0; c < 8; ++c) s += r[lane + 64 * c] * v2[lane + 64 * c];
    for (int d = 32; d >= 1; d >>= 1) s += __shfl_xor(s, d, 64);
    if (lane == 0){
      int b = row / NCHUNK, n = row % NCHUNK;
      betag[b * LGLD + n] = s + gbuf[0];
    }
  }
}

// ---------------- logits (NN form): 2 rows/wave, grid (16,10,NB) ----------------
__global__ __launch_bounds__(256) void logits_nn(const float* __restrict__ u_ext,
                                                 const float* __restrict__ summText,
                                                 const float* __restrict__ betag,
                                                 const float* __restrict__ chunkden,
                                                 float* __restrict__ logits){
  int b = blockIdx.z;
  int tid = threadIdx.x;
  int lane = tid & 63, w = tid >> 6;
  int r0 = blockIdx.x * 8 + w * 2;       // i
  int n  = blockIdx.y * 64 + lane;
  const float* a0 = u_ext + ((long)b * QN + r0) * W2LD;
  const float* bp = summText + (long)b * STROWS * LGLD + n;
  float acc0 = 0.f, acc1 = 0.f;
#pragma unroll 4
  for (int k = 0; k < STROWS; k += 4){
    float b0 = bp[(long)k * LGLD];
    float b1 = bp[(long)(k + 1) * LGLD];
    float b2 = bp[(long)(k + 2) * LGLD];
    float b3 = bp[(long)(k + 3) * LGLD];
    float4 a;
    a = *(const float4*)(a0 + k);
    acc0 += a.x * b0 + a.y * b1 + a.z * b2 + a.w * b3;
    a = *(const float4*)(a0 + W2LD + k);
    acc1 += a.x * b0 + a.y * b1 + a.z * b2 + a.w * b3;
  }
  if (n < NCHUNK){
    float bet = betag[b * LGLD + n];
    bool dead = (chunkden[b * NCHUNK + n] <= 0.f);
    float v0 = (acc0 + bet) * LOGIT_SCALE;
    float v1 = (acc1 + bet) * LOGIT_SCALE;
    if (dead){ v0 = v1 = -FLT_MAX; }
    long base = ((long)b * QN + r0) * LGLD + n;
    logits[base]        = v0;
    logits[base + LGLD] = v1;
  }
}

// ---------------- top-8 + softmax weights, 4 waves per (b,i) row ----------------
__global__ __launch_bounds__(256) void topk_kernel(const float* __restrict__ logits,
                                                   int* __restrict__ topi_out,
                                                   float* __restrict__ wts_out){
  int row = blockIdx.x;   // b*128+i
  __shared__ float lds[NCHUNK];
  __shared__ float wv[4];
  __shared__ int   wi[4];
  __shared__ float topv[TOPKK];
  __shared__ int   topi[TOPKK];
  int t = threadIdx.x;
  int lane = t & 63, w = t >> 6;
  for (int idx = t; idx < NCHUNK; idx += 256) lds[idx] = logits[(long)row * LGLD + idx];
  __syncthreads();
  for (int it = 0; it < TOPKK; ++it){
    float bv = -INFINITY; int bi = 0x7fffffff;
    for (int idx = t; idx < NCHUNK; idx += 256){
      float v = lds[idx];
      if (v > bv){ bv = v; bi = idx; }
    }
    for (int d = 32; d >= 1; d >>= 1){
      float ov = __shfl_xor(bv, d, 64);
      int   oi = __shfl_xor(bi, d, 64);
      if (ov > bv || (ov == bv && oi < bi)){ bv = ov; bi = oi; }
    }
    if (lane == 0){ wv[w] = bv; wi[w] = bi; }
    __syncthreads();
    if (t == 0){
      float fb = wv[0]; int fi = wi[0];
      for (int j = 1; j < 4; ++j){
        if (wv[j] > fb || (wv[j] == fb && wi[j] < fi)){ fb = wv[j]; fi = wi[j]; }
      }
      topv[it] = fb; topi[it] = fi; lds[fi] = -INFINITY;
    }
    __syncthreads();
  }
  if (t == 0){
    float m = topv[0];
    for (int r = 1; r < TOPKK; ++r) m = fmaxf(m, topv[r]);
    float e[TOPKK], s = 0.f;
    for (int r = 0; r < TOPKK; ++r){ e[r] = expf(topv[r] - m); s += e[r]; }
    for (int r = 0; r < TOPKK; ++r){
      wts_out[(long)row * TOPKK + r] = e[r] / s;
      topi_out[(long)row * TOPKK + r] = topi[r];
    }
  }
}

// ---------------- KV GEMM, dbuf, XCD-aware remap, multi-batch ----------------
__global__ __launch_bounds__(256) void kv_gemm(const unsigned short* __restrict__ A_all,
                                               const unsigned short* __restrict__ Bt,
                                               unsigned short* __restrict__ kv_all,
                                               int npanels){
  int L = blockIdx.x;
  int panel = ((L >> 6) << 3) | (L & 7);
  int nb = (L >> 3) & 7;
  if (panel >= npanels) return;
  int bb = panel / 157;
  int p  = panel - bb * 157;
  const unsigned short* A = A_all + (size_t)bb * MPAD * 512;
  unsigned short* kvout   = kv_all + (size_t)bb * MPAD * NKV;

  __shared__ unsigned short As[2][128 * 32];
  __shared__ unsigned short Bs[2][128 * 32];
  int m0 = p << 7, n0 = nb << 7;
  int tid = threadIdx.x;
  int wid = tid >> 6, lane = tid & 63;
  int wr = wid >> 1, wc = wid & 1;
  int lr = lane & 15, lg = lane >> 4;

  int srow = wid * 16 + (lane >> 2);
  int scol = (lane & 3) << 3;
  const unsigned short* gA0 = A  + (long)(m0 + srow) * 512 + scol;
  const unsigned short* gA1 = gA0 + 64 * 512;
  const unsigned short* gB0 = Bt + (long)(n0 + srow) * 512 + scol;
  const unsigned short* gB1 = gB0 + 64 * 512;
  int lofs0 = (wid * 16) * 32;
  int lofs1 = (64 + wid * 16) * 32;

  f32x4 acc[4][4];
#pragma unroll
  for (int i = 0; i < 4; ++i)
#pragma unroll
    for (int j = 0; j < 4; ++j) acc[i][j] = (f32x4)0.f;

#define STAGE(B, K0) { gload16(gA0 + (K0), &As[B][lofs0]); gload16(gA1 + (K0), &As[B][lofs1]); \
                       gload16(gB0 + (K0), &Bs[B][lofs0]); gload16(gB1 + (K0), &Bs[B][lofs1]); }
#define COMPUTE(B) { bf16x8 af[4], bfv[4]; \
  _Pragma("unroll") for (int mi = 0; mi < 4; ++mi) af[mi]  = *(const bf16x8*)&As[B][(wr * 64 + mi * 16 + lr) * 32 + lg * 8]; \
  _Pragma("unroll") for (int ni = 0; ni < 4; ++ni) bfv[ni] = *(const bf16x8*)&Bs[B][(wc * 64 + ni * 16 + lr) * 32 + lg * 8]; \
  _Pragma("unroll") for (int mi = 0; mi < 4; ++mi) \
    _Pragma("unroll") for (int ni = 0; ni < 4; ++ni) \
      acc[mi][ni] = __builtin_amdgcn_mfma_f32_16x16x32_bf16(af[mi], bfv[ni], acc[mi][ni], 0, 0, 0); }

  STAGE(0, 0);
  __syncthreads();
#pragma unroll 1
  for (int t = 0; t < 16; t += 2){
    if (t + 1 < 16) STAGE(1, (t + 1) * 32);
    COMPUTE(0);
    __syncthreads();
    if (t + 2 < 16) STAGE(0, (t + 2) * 32);
    COMPUTE(1);
    __syncthreads();
  }
#undef STAGE
#undef COMPUTE

#pragma unroll
  for (int mi = 0; mi < 4; ++mi)
#pragma unroll
    for (int ni = 0; ni < 4; ++ni)
#pragma unroll
      for (int rr = 0; rr < 4; ++rr){
        int gr = m0 + wr * 64 + mi * 16 + lg * 4 + rr;
        int gn = n0 + wc * 64 + ni * 16 + lr;
        kvout[(long)gr * NKV + gn] = (unsigned short)f2bf(acc[mi][ni][rr]);
      }
}

// ---------------- attention; bb_arg<0 => batched (grid 4096, per-batch kv stride) ----------------
__global__ __launch_bounds__(256) void attn_kernel(const float* __restrict__ qh,
                                                   const unsigned short* __restrict__ kv,
                                                   const int* __restrict__ topidx,
                                                   const float* __restrict__ wts,
                                                   const void* __restrict__ mask,
                                                   const int* __restrict__ flagp,
                                                   float* __restrict__ osc,
                                                   int bb_arg){
  int bx = blockIdx.x;
  int bb, rem;
  const unsigned short* kvb;
  if (bb_arg < 0){
    bb = bx >> 10; rem = bx & 1023;
    kvb = kv + (size_t)bb * MPAD * NKV;
  } else {
    bb = bb_arg; rem = bx;
    kvb = kv;
  }
  int i = rem >> 3, k = rem & 7;
  int t = threadIdx.x;
  __shared__ float qs[HID];
  __shared__ float att[HEADS][CHUNK + 1];
  int flag = *flagp;
  long sel = ((long)(bb * QN + i)) * TOPKK + k;
  int chunk = topidx[sel];
  float w8 = wts[sel];
  const float* qrow = qh + ((long)(bb * QN + i)) * HID;
  qs[t] = qrow[t]; qs[t + 256] = qrow[t + 256];
  __syncthreads();
  int h = t >> 5, c = t & 31;
  const unsigned short* krow = kvb + ((long)(chunk * CHUNK + c)) * NKV + h * DHEAD;
  float s = 0.f;
#pragma unroll
  for (int e8 = 0; e8 < 8; ++e8){
    bf16x8 k8 = *(const bf16x8*)(krow + e8 * 8);
#pragma unroll
    for (int j = 0; j < 8; ++j) s += qs[h * DHEAD + e8 * 8 + j] * bf2f((unsigned short)k8[j]);
  }
  bool mv = mask_at(mask, flag, (long)bb * NMEM + (long)chunk * CHUNK + c);
  if (!mv) s = -FLT_MAX;
  float m = s;
  for (int d = 16; d >= 1; d >>= 1) m = fmaxf(m, __shfl_xor(m, d, 32));
  float p = expf(s - m);
  float su = p;
  for (int d = 16; d >= 1; d >>= 1) su += __shfl_xor(su, d, 32);
  att[h][c] = p / su;
  __syncthreads();
  int e0 = (t & 31) * 2;
  float o0 = 0.f, o1 = 0.f;
#pragma unroll 8
  for (int c2 = 0; c2 < CHUNK; ++c2){
    float a = att[h][c2];
    unsigned int pv = *(const unsigned int*)(kvb + ((long)(chunk * CHUNK + c2)) * NKV + 512 + h * DHEAD + e0);
    o0 += a * bf2f((unsigned short)(pv & 0xffff));
    o1 += a * bf2f((unsigned short)(pv >> 16));
  }
  long ob = (((long)(bb * QN + i) * TOPKK) + k) * HID + h * DHEAD + e0;
  osc[ob]     = o0 * w8;
  osc[ob + 1] = o1 * w8;
}

// ---------------- final: reduce over k, then @ (out_w@fc2_w) + folded bias ----------------
__global__ __launch_bounds__(512) void final_kernel(const float* __restrict__ osc,
                                                    const float* __restrict__ Wf,
                                                    const float* __restrict__ bfold,
                                                    float* __restrict__ out){
  int bi = blockIdx.x;   // b*128+i
  int t = threadIdx.x;
  __shared__ float lds[HID];
  float s = 0.f;
  for (int k = 0; k < TOPKK; ++k) s += osc[(((long)bi * TOPKK) + k) * HID + t];
  lds[t] = s;
  __syncthreads();
  int w = t >> 6, lane = t & 63;
  if (w < 5){
    float a = 0.f;
#pragma unroll
    for (int c = 0; c < 8; ++c) a += lds[lane + 64 * c] * Wf[(lane + 64 * c) * 5 + w];
    for (int d = 32; d >= 1; d >>= 1) a += __shfl_xor(a, d, 64);
    if (lane == 0) out[bi * 5 + w] = a + bfold[w];
  }
}

extern "C" void kernel_launch(void* const* d_in, const int* in_sizes, int n_in,
                              void* d_out, int out_size, void* d_ws, size_t ws_size,
                              hipStream_t stream) {
  const float* queries  = (const float*)d_in[1];
  const float* memories = (const float*)d_in[2];
  const void*  mask     = d_in[3];
  const float* sq_w = (const float*)d_in[10];
  const float* sq_b = (const float*)d_in[11];
  const float* sk_w = (const float*)d_in[12];
  const float* sk_b = (const float*)d_in[13];
  const float* q_w  = (const float*)d_in[14];
  const float* kv_w = (const float*)d_in[15];
  const float* out_w = (const float*)d_in[16];
  const float* out_b = (const float*)d_in[17];
  const float* fc2_w = (const float*)d_in[18];
  const float* fc2_b = (const float*)d_in[19];
  float* out = (float*)d_out;

  char* ws = (char*)d_ws;
  size_t o_sum  = 0;                        // 5,120,000
  size_t o_den  = o_sum + 5120000;          // 10,240
  size_t o_pos  = o_den + 10240;            // 65,536
  size_t o_wf   = o_pos + 65536;            // 10,240
  size_t o_bf   = o_wf  + 10240;            // 512
  size_t o_ti   = o_bf  + 512;              // 16,384
  size_t o_wt   = o_ti  + 16384;            // 16,384
  size_t o_flag = o_wt  + 16384;            // 512
  size_t o_qh   = o_flag + 512;             // 1,048,576
  size_t o_w2   = o_qh  + 1048576;          // 1,179,648
  size_t o_uex  = o_w2  + 1179648;          // 1,179,648
  size_t o_st   = o_uex + 1179648;          // 5,324,800
  size_t o_bg   = o_st  + 5324800;          // 10,240
  size_t o_v2   = o_bg  + 10240;            // 2,048
  size_t o_gm   = o_v2  + 2048;             // 512
  size_t o_lg   = o_gm  + 512;              // 1,310,720
  size_t o_osc  = o_lg  + 1310720;          // 8,388,608
  size_t o_skt  = o_osc + 8388608;          // 1,048,576
  size_t o_abf  = o_skt + 1048576;

  const size_t ABF_ONE = (size_t)MPAD * 512 * 2;          // 20,578,304
  const size_t ABF_ALL = ABF_ONE * NB;                    // 82,313,216
  const size_t KV_ONE  = (size_t)MPAD * NKV * 2;          // 41,156,608
  size_t need_fused   = o_abf + ABF_ALL + 1048576 + KV_ONE;
  size_t need_batched = o_abf + ABF_ALL + 1048576 + KV_ONE * NB;
  bool fused   = (ws_size >= need_fused);
  bool batched = (ws_size >= need_batched);
  size_t abf_bytes = fused ? ABF_ALL : ABF_ONE;
  size_t o_btw = o_abf + abf_bytes;
  size_t o_kv  = o_btw + 1048576;

  float* summ  = (float*)(ws + o_sum);
  float* den   = (float*)(ws + o_den);
  float* pos   = (float*)(ws + o_pos);
  float* Wf    = (float*)(ws + o_wf);
  float* bfold = (float*)(ws + o_bf);
  int*   ti    = (int*)  (ws + o_ti);
  float* wt    = (float*)(ws + o_wt);
  int*   flagp = (int*)  (ws + o_flag);
  float* qh    = (float*)(ws + o_qh);
  float* W2buf = (float*)(ws + o_w2);
  float* u_ext = (float*)(ws + o_uex);
  float* summText = (float*)(ws + o_st);
  float* betag = (float*)(ws + o_bg);
  float* v2    = (float*)(ws + o_v2);
  float* gbuf  = (float*)(ws + o_gm);
  float* logit = (float*)(ws + o_lg);
  float* osc   = (float*)(ws + o_osc);
  float* skwT  = (float*)(ws + o_skt);
  unsigned short* abf   = (unsigned short*)(ws + o_abf);
  unsigned short* btw   = (unsigned short*)(ws + o_btw);
  unsigned short* kvbuf = (unsigned short*)(ws + o_kv);

  setup_kernel<<<dim3(271), dim3(256), 0, stream>>>(
      kv_w, sk_w, mask, out_w, out_b, fc2_w, fc2_b, sq_w, sq_b, sk_b,
      btw, skwT, pos, flagp, Wf, bfold, W2buf, v2, gbuf);

  prepsum_kernel<<<dim3(NCHUNK + 1, NB), dim3(512), 0, stream>>>(
      memories, pos, mask, flagp, fused ? abf : nullptr, summ, den);

  if (batched){
    // kv projection for all batches right after its inputs are ready
    kv_gemm<<<dim3(((NB * 157 + 7) / 8) * 64), dim3(256), 0, stream>>>(abf, btw, kvbuf, NB * 157);
  }

  // selection path (f32-exact)
  gemm_nn<<<dim3(32, 8), dim3(256), 0, stream>>>(sq_w, 512, skwT, 512, W2buf, W2LD, 512, 1.0f);
  uq_kernel<<<dim3(64, 17), dim3(256), 0, stream>>>(queries, W2buf, q_w, u_ext, qh);
  stbeta_kernel<<<dim3(949), dim3(256), 0, stream>>>(summ, v2, gbuf, summText, betag);
  logits_nn<<<dim3(16, 10, NB), dim3(256), 0, stream>>>(u_ext, summText, betag, den, logit);
  topk_kernel<<<dim3(NB * QN), dim3(256), 0, stream>>>(logit, ti, wt);

  if (batched){
    attn_kernel<<<dim3(NB * QN * TOPKK), dim3(256), 0, stream>>>(qh, kvbuf, ti, wt, mask, flagp, osc, -1);
  } else {
    for (int bb = 0; bb < NB; ++bb){
      const unsigned short* Ab;
      if (fused){
        Ab = abf + (size_t)bb * MPAD * 512;
      } else {
        prep_kernel<<<dim3(10048), dim3(256), 0, stream>>>(memories + (long)bb * NMEM * HID, pos, abf);
        Ab = abf;
      }
      kv_gemm<<<dim3(((157 + 7) / 8) * 64), dim3(256), 0, stream>>>(Ab, btw, kvbuf, 157);
      attn_kernel<<<dim3(QN * TOPKK), dim3(256), 0, stream>>>(qh, kvbuf, ti, wt, mask, flagp, osc, bb);
    }
  }
  final_kernel<<<dim3(NB * QN), dim3(512), 0, stream>>>(osc, Wf, bfold, out);
}